// Round 7
// baseline (280.390 us; speedup 1.0000x reference)
//
#include <hip/hip_runtime.h>
#include <hip/hip_bf16.h>

#define B_ 4
#define S_ 1024
#define E_ 1024
#define H_ 16
#define D_ 64

typedef __attribute__((ext_vector_type(8))) short short8;
typedef __attribute__((ext_vector_type(4))) float f32x4;

static __device__ __forceinline__ unsigned short f2bf(float x) {
  unsigned int u = __float_as_uint(x);
  unsigned int r = u + 0x7fffu + ((u >> 16) & 1u);  // round-to-nearest-even
  return (unsigned short)(r >> 16);
}
static __device__ __forceinline__ float bf2f(unsigned short b) {
  return __uint_as_float((unsigned int)b << 16);
}

#define GL2LDS16(g, l)                                                            \
  __builtin_amdgcn_global_load_lds(                                               \
      (const __attribute__((address_space(1))) unsigned int*)(g),                 \
      (__attribute__((address_space(3))) unsigned int*)(l), 16, 0, 0)

// combined scale: (1/sqrt(D)) * log2(e) applied in-register to the MFMA score,
// so exp() is a single v_exp_f32 (2^x). Q/K stored UNSCALED.
#define QSCALE 0.18033688011112042f
#define SCLAMP 115.41560327111707f  // 80 * log2(e)

// 16-lane sum via DPP (no LDS pipe): xor1, xor2, half-mirror, row-mirror.
// After this, ALL 16 lanes of each group hold the full sum.
static __device__ __forceinline__ float dpp_red16(float v) {
  v += __int_as_float(__builtin_amdgcn_update_dpp(0, __float_as_int(v), 0xB1, 0xF, 0xF, true));   // quad_perm [1,0,3,2]
  v += __int_as_float(__builtin_amdgcn_update_dpp(0, __float_as_int(v), 0x4E, 0xF, 0xF, true));   // quad_perm [2,3,0,1]
  v += __int_as_float(__builtin_amdgcn_update_dpp(0, __float_as_int(v), 0x141, 0xF, 0xF, true));  // row_half_mirror
  v += __int_as_float(__builtin_amdgcn_update_dpp(0, __float_as_int(v), 0x140, 0xF, 0xF, true));  // row_mirror
  return v;
}

// ---------- fused preprocessing: mask|mask^T, x->bf16, W->Wt bf16 ----------
// blocks 0..4095: mask_sym; 4096..6143: cvt_x; 6144..8191: wt transpose
__global__ __launch_bounds__(256) void prep_kernel(const int* __restrict__ mask,
                                                   const float* __restrict__ x,
                                                   const float* __restrict__ Wq,
                                                   const float* __restrict__ Wk,
                                                   unsigned char* __restrict__ msym,
                                                   unsigned short* __restrict__ xbf,
                                                   unsigned short* __restrict__ Wt) {
  __shared__ __align__(16) char u_lds[32 * 33 * 4];
  const int blk = blockIdx.x;
  const int tid = threadIdx.x;
  if (blk < 4096) {
    int (*T)[33] = (int(*)[33])u_lds;
    const int b = blk >> 10;
    const int rest = blk & 1023;
    const int i0 = (rest >> 5) << 5;
    const int j0 = (rest & 31) << 5;
    const int ii = tid >> 3;
    const int jj4 = (tid & 7) << 2;
    const size_t bO = (size_t)b * S_ * S_;
    const int4 m2 = *(const int4*)&mask[bO + (size_t)(j0 + ii) * S_ + i0 + jj4];
    T[ii][jj4 + 0] = m2.x; T[ii][jj4 + 1] = m2.y; T[ii][jj4 + 2] = m2.z; T[ii][jj4 + 3] = m2.w;
    __syncthreads();
    const int4 m1 = *(const int4*)&mask[bO + (size_t)(i0 + ii) * S_ + j0 + jj4];
    uchar4 o;
    o.x = ((m1.x != 0) || (T[jj4 + 0][ii] != 0)) ? 1 : 0;
    o.y = ((m1.y != 0) || (T[jj4 + 1][ii] != 0)) ? 1 : 0;
    o.z = ((m1.z != 0) || (T[jj4 + 2][ii] != 0)) ? 1 : 0;
    o.w = ((m1.w != 0) || (T[jj4 + 3][ii] != 0)) ? 1 : 0;
    *(uchar4*)&msym[bO + (size_t)(i0 + ii) * S_ + j0 + jj4] = o;
  } else if (blk < 6144) {
    const size_t i = ((size_t)(blk - 4096) * 256 + tid) * 8;
    const float4 a = *(const float4*)(x + i);
    const float4 b = *(const float4*)(x + i + 4);
    const ushort4 p0 = {f2bf(a.x), f2bf(a.y), f2bf(a.z), f2bf(a.w)};
    const ushort4 p1 = {f2bf(b.x), f2bf(b.y), f2bf(b.z), f2bf(b.w)};
    *(ushort4*)(xbf + i) = p0;
    *(ushort4*)(xbf + i + 4) = p1;
  } else {
    unsigned short (*T2)[36] = (unsigned short(*)[36])u_lds;
    const int wblk = blk - 6144;           // 2 * 32 * 32
    const int mat = wblk >> 10;
    const int kt = (wblk >> 5) & 31, ntb = wblk & 31;
    const float* W = mat ? Wk : Wq;
    const int r = tid >> 3, c4 = (tid & 7) << 2;
    const float4 v = *(const float4*)&W[(size_t)(kt * 32 + r) * 1024 + ntb * 32 + c4];
    T2[r][c4 + 0] = f2bf(v.x); T2[r][c4 + 1] = f2bf(v.y);
    T2[r][c4 + 2] = f2bf(v.z); T2[r][c4 + 3] = f2bf(v.w);
    __syncthreads();
    const ushort4 o = {T2[c4 + 0][r], T2[c4 + 1][r], T2[c4 + 2][r], T2[c4 + 3][r]};
    *(ushort4*)&Wt[(size_t)(mat * 1024 + ntb * 32 + r) * 1024 + kt * 32 + c4] = o;
  }
}

// ------- bf16 MFMA GEMM, BK=64: P[4096][nstride] = xbf[4096][1024] @ Wt^T --------
__global__ __launch_bounds__(256) void gemm_mfma_kernel(const unsigned short* __restrict__ Abf,
                                                        const unsigned short* __restrict__ Wt,
                                                        unsigned short* __restrict__ P,
                                                        int nstride) {
  __shared__ __align__(16) unsigned short As[128 * 64];  // 16 KB, [m][k]
  __shared__ __align__(16) unsigned short Bs[128 * 64];  // 16 KB, [n][k]
  const int tid = threadIdx.x;
  const int m0 = (blockIdx.x & 31) << 7;
  const int n0 = (blockIdx.x >> 5) << 7;
  const int wave = tid >> 6, lane = tid & 63;
  const int ln15 = lane & 15, rg = lane >> 4;
  const int wm = (wave & 1) << 6;
  const int wn = (wave >> 1) << 6;
  const int sr = tid >> 3;
  const int sc = (tid & 7) << 3;
  const unsigned short* gA = Abf + (size_t)(m0 + sr) * 1024 + sc;
  const unsigned short* gB = Wt + (size_t)(n0 + sr) * 1024 + sc;
  unsigned short* lA = As + tid * 8;
  unsigned short* lB = Bs + tid * 8;
  f32x4 acc[4][4];
#pragma unroll
  for (int i = 0; i < 4; ++i)
#pragma unroll
    for (int j = 0; j < 4; ++j) acc[i][j] = (f32x4){0.0f, 0.0f, 0.0f, 0.0f};

  const unsigned short* pa = As + (wm + ln15) * 64 + rg * 8;
  const unsigned short* pb = Bs + (wn + ln15) * 64 + rg * 8;
  for (int k0 = 0; k0 < E_; k0 += 64) {
#pragma unroll
    for (int j = 0; j < 4; ++j) {
      GL2LDS16(gA + k0 + (size_t)(j * 32) * 1024, lA + j * 2048);
      GL2LDS16(gB + k0 + (size_t)(j * 32) * 1024, lB + j * 2048);
    }
    __syncthreads();
#pragma unroll
    for (int kk = 0; kk < 2; ++kk) {
      short8 af[4], bfr[4];
#pragma unroll
      for (int i = 0; i < 4; ++i) af[i] = *(const short8*)(pa + i * 16 * 64 + kk * 32);
#pragma unroll
      for (int j = 0; j < 4; ++j) bfr[j] = *(const short8*)(pb + j * 16 * 64 + kk * 32);
#pragma unroll
      for (int i = 0; i < 4; ++i)
#pragma unroll
        for (int j = 0; j < 4; ++j)
          acc[i][j] = __builtin_amdgcn_mfma_f32_16x16x32_bf16(af[i], bfr[j], acc[i][j], 0, 0, 0);
    }
    __syncthreads();
  }
#pragma unroll
  for (int i = 0; i < 4; ++i)
#pragma unroll
    for (int j = 0; j < 4; ++j)
#pragma unroll
      for (int r = 0; r < 4; ++r) {
        const int row = m0 + wm + i * 16 + rg * 4 + r;
        const int col = n0 + wn + j * 16 + ln15;
        P[(size_t)row * nstride + col] = f2bf(acc[i][j][r]);
      }
}

// ---- bias+LN+ReLU from bf16 P; emit bf16 head-major [b*16+h][s][d] ----
__device__ __forceinline__ void ln_body(const unsigned short* p, const float* bias,
                                        const float* gamma, const float* beta,
                                        unsigned short* obf, int b, int s, int tid) {
  const ushort4 pv = *(const ushort4*)(p + tid * 4);
  float4 v = {bf2f(pv.x), bf2f(pv.y), bf2f(pv.z), bf2f(pv.w)};
  const float4 bb = ((const float4*)bias)[tid];
  v.x += bb.x; v.y += bb.y; v.z += bb.z; v.w += bb.w;
  float sum = v.x + v.y + v.z + v.w;
  float s2 = v.x * v.x + v.y * v.y + v.z * v.z + v.w * v.w;
#pragma unroll
  for (int off = 32; off >= 1; off >>= 1) {
    sum += __shfl_xor(sum, off);
    s2 += __shfl_xor(s2, off);
  }
  __shared__ float red[2][4];
  const int wave = tid >> 6, lane = tid & 63;
  if (lane == 0) { red[0][wave] = sum; red[1][wave] = s2; }
  __syncthreads();
  sum = red[0][0] + red[0][1] + red[0][2] + red[0][3];
  s2 = red[1][0] + red[1][1] + red[1][2] + red[1][3];
  const float mu = sum * (1.0f / E_);
  const float var = s2 * (1.0f / E_) - mu * mu;
  const float r = rsqrtf(var + 1e-5f);
  const float4 g = ((const float4*)gamma)[tid];
  const float4 bt = ((const float4*)beta)[tid];
  const float o0 = fmaxf((v.x - mu) * r * g.x + bt.x, 0.0f);
  const float o1 = fmaxf((v.y - mu) * r * g.y + bt.y, 0.0f);
  const float o2 = fmaxf((v.z - mu) * r * g.z + bt.z, 0.0f);
  const float o3 = fmaxf((v.w - mu) * r * g.w + bt.w, 0.0f);
  const int h = tid >> 4;
  const int d = (tid & 15) << 2;
  const ushort4 ob = {f2bf(o0), f2bf(o1), f2bf(o2), f2bf(o3)};
  *(ushort4*)&obf[((size_t)(b * H_ + h) * S_ + s) * D_ + d] = ob;
}

__global__ __launch_bounds__(256) void ln_relu_bf_kernel(const unsigned short* __restrict__ P,
                                                         int rowstride, int coloff,
                                                         const float* __restrict__ bias,
                                                         const float* __restrict__ gamma,
                                                         const float* __restrict__ beta,
                                                         unsigned short* __restrict__ obf) {
  const int row = blockIdx.x;
  ln_body(P + (size_t)row * rowstride + coloff, bias, gamma, beta, obf,
          row >> 10, row & 1023, threadIdx.x);
}

// fused both-LN launch (40MB path): blocks 0..4095 -> Q, 4096..8191 -> K
__global__ __launch_bounds__(256) void ln2_kernel(const unsigned short* __restrict__ P2,
                                                  const float* __restrict__ bq,
                                                  const float* __restrict__ gq,
                                                  const float* __restrict__ bqn,
                                                  const float* __restrict__ bk,
                                                  const float* __restrict__ gk,
                                                  const float* __restrict__ bkn,
                                                  unsigned short* __restrict__ Qbf,
                                                  unsigned short* __restrict__ Kbf) {
  const int blk = blockIdx.x;
  const int sel = blk >> 12;
  const int row = blk & 4095;
  ln_body(P2 + (size_t)row * 2048 + sel * 1024,
          sel ? bk : bq, sel ? gk : gq, sel ? bkn : bqn,
          sel ? Kbf : Qbf, row >> 10, row & 1023, threadIdx.x);
}

// ======= attention v16: two barrier-free passes (denominators, then output) ====
// out[b,q,k] = (1/16) * sum_h exp(s_h(q,k)) * inv_l[b,h,q]. Once inv_l is known,
// the k-reduction vanishes from the output pass: every (q,k) is independent.
// QK^T is computed twice (MFMA was at 6% util - free); in exchange ALL barriers,
// ALL cross-wave reductions, and the 128KB LDS staging disappear, and occupancy
// rises to 4 independent 256-thr blocks/CU whose TLP hides L2 latency (v13's
// failure mode was 1 lockstep block/CU). Fragment mapping identical to the
// correctness-verified v13 direct-load path.

// Pass A: inv_l[b,h,q]. grid (b,h,qt64) = 1024 blocks x 4 waves.
// Each wave owns 16 q-rows x ALL 1024 keys -> l is wave-local (DPP only).
__global__ __launch_bounds__(256, 4) void attn_l_kernel(const unsigned short* __restrict__ Qbf,
                                                        const unsigned short* __restrict__ Kbf,
                                                        const unsigned char* __restrict__ msym,
                                                        float* __restrict__ linv) {
  const int tid = threadIdx.x;
  const int wave = tid >> 6, lane = tid & 63;
  const int ln15 = lane & 15, rg = lane >> 4;
  const int blk = blockIdx.x;
  const int b = blk >> 8;
  const int h = (blk >> 4) & 15;
  const int qt = blk & 15;
  const int q0 = qt * 64 + wave * 16;
  const size_t bh = (size_t)(b * H_ + h);
  const unsigned short* qp = Qbf + (bh * S_ + q0 + ln15) * D_ + rg * 8;
  const short8 a0 = *(const short8*)qp;
  const short8 a1 = *(const short8*)(qp + 32);
  const unsigned short* kp = Kbf + (bh * S_ + ln15) * D_ + rg * 8;
  const unsigned char* mrow = msym + ((size_t)b * S_ + q0 + rg * 4) * S_ + ln15;
  float la[4] = {0.0f, 0.0f, 0.0f, 0.0f};
#pragma unroll 2
  for (int c = 0; c < 16; ++c) {
#pragma unroll
    for (int t = 0; t < 4; ++t) {
      const int kbase = c * 64 + t * 16;
      const unsigned short* kf = kp + (size_t)kbase * D_;
      const short8 b0 = *(const short8*)kf;
      const short8 b1 = *(const short8*)(kf + 32);
      f32x4 cc = {0.0f, 0.0f, 0.0f, 0.0f};
      cc = __builtin_amdgcn_mfma_f32_16x16x32_bf16(a0, b0, cc, 0, 0, 0);
      cc = __builtin_amdgcn_mfma_f32_16x16x32_bf16(a1, b1, cc, 0, 0, 0);
#pragma unroll
      for (int r = 0; r < 4; ++r) {
        const unsigned char m = mrow[(size_t)r * S_ + kbase];
        const float sv = fminf(cc[r] * QSCALE, SCLAMP);
        const float ev = __builtin_amdgcn_exp2f(sv);
        la[r] += m ? 0.0f : ev;
      }
    }
  }
#pragma unroll
  for (int r = 0; r < 4; ++r) la[r] = dpp_red16(la[r]);
  if (ln15 == 0) {
    const f32x4 wv = {__builtin_amdgcn_rcpf(la[0]), __builtin_amdgcn_rcpf(la[1]),
                      __builtin_amdgcn_rcpf(la[2]), __builtin_amdgcn_rcpf(la[3])};
    *(f32x4*)&linv[bh * S_ + q0 + rg * 4] = wv;
  }
}

// Pass B: output. grid (b,qt64,kt64) = 1024 blocks x 4 waves.
// Wave: 16q x 64k tile, loop 16 heads accumulating exp2(score)*mf*inv_l.
// No barriers, no LDS; 4 waves of a block share K fragments (L1 hits).
__global__ __launch_bounds__(256, 4) void attn_o_kernel(const unsigned short* __restrict__ Qbf,
                                                        const unsigned short* __restrict__ Kbf,
                                                        const unsigned char* __restrict__ msym,
                                                        const float* __restrict__ linv,
                                                        float* __restrict__ out) {
  const int tid = threadIdx.x;
  const int wave = tid >> 6, lane = tid & 63;
  const int ln15 = lane & 15, rg = lane >> 4;
  const int blk = blockIdx.x;
  const int b = blk >> 8;
  const int qt = (blk >> 4) & 15;
  const int kt = blk & 15;
  const int q0 = qt * 64 + wave * 16;
  const int k0 = kt * 64;
  // mask -> {0,1} float multipliers, reused across all 16 heads
  float mf[4][4];
#pragma unroll
  for (int t = 0; t < 4; ++t)
#pragma unroll
    for (int r = 0; r < 4; ++r)
      mf[t][r] = msym[((size_t)b * S_ + q0 + rg * 4 + r) * S_ + k0 + t * 16 + ln15] ? 0.0f : 1.0f;

  const unsigned short* qp = Qbf + ((size_t)(b * H_) * S_ + q0 + ln15) * D_ + rg * 8;
  const unsigned short* kp = Kbf + ((size_t)(b * H_) * S_ + k0 + ln15) * D_ + rg * 8;
  const float* lp = linv + (size_t)(b * H_) * S_ + q0 + rg * 4;
  const size_t HD = (size_t)S_ * D_;

  float o[4][4] = {};
#pragma unroll 1
  for (int h = 0; h < 16; ++h) {
    const short8 a0 = *(const short8*)qp;
    const short8 a1 = *(const short8*)(qp + 32);
    const f32x4 li = *(const f32x4*)lp;  // rows rg*4..+3, broadcast across ln15
#pragma unroll
    for (int t = 0; t < 4; ++t) {
      const unsigned short* kf = kp + (size_t)(t * 16) * D_;
      const short8 b0 = *(const short8*)kf;
      const short8 b1 = *(const short8*)(kf + 32);
      f32x4 cc = {0.0f, 0.0f, 0.0f, 0.0f};
      cc = __builtin_amdgcn_mfma_f32_16x16x32_bf16(a0, b0, cc, 0, 0, 0);
      cc = __builtin_amdgcn_mfma_f32_16x16x32_bf16(a1, b1, cc, 0, 0, 0);
#pragma unroll
      for (int r = 0; r < 4; ++r) {
        const float sv = fminf(cc[r] * QSCALE, SCLAMP);
        const float ev = __builtin_amdgcn_exp2f(sv) * mf[t][r];
        o[t][r] += ev * li[r];
      }
    }
    qp += HD; kp += HD; lp += S_;
  }
  // stores: 64B contiguous per (t,r) across the 16 key-lanes; 1/16 head-mean here
#pragma unroll
  for (int t = 0; t < 4; ++t)
#pragma unroll
    for (int r = 0; r < 4; ++r)
      out[((size_t)b * S_ + q0 + rg * 4 + r) * S_ + k0 + t * 16 + ln15] = o[t][r] * 0.0625f;
}

extern "C" void kernel_launch(void* const* d_in, const int* in_sizes, int n_in,
                              void* d_out, int out_size, void* d_ws, size_t ws_size,
                              hipStream_t stream) {
  const float* x = (const float*)d_in[0];
  const int* mask = (const int*)d_in[1];
  const float* Wq = (const float*)d_in[2];
  const float* bq = (const float*)d_in[3];
  const float* Wk = (const float*)d_in[4];
  const float* bk = (const float*)d_in[5];
  const float* gq = (const float*)d_in[6];
  const float* bq_n = (const float*)d_in[7];
  const float* gk = (const float*)d_in[8];
  const float* bk_n = (const float*)d_in[9];
  float* out = (float*)d_out;

  char* ws = (char*)d_ws;
  const size_t MB = 1024 * 1024;

  if (ws_size >= 40 * MB) {
    // fused layout (40 MB): P2 bf16 [4096][2048] @0 (16), xbf @16 (8, Kbf aliases),
    // Wt @24 (4), Qbf @28 (8), msym @36 (4); linv aliases Wt (dead after gemm)
    unsigned short* P2 = (unsigned short*)ws;
    unsigned short* xbf = (unsigned short*)(ws + 16 * MB);
    unsigned short* Kbf = (unsigned short*)(ws + 16 * MB);   // alias: xbf dead after gemm
    unsigned short* Wt = (unsigned short*)(ws + 24 * MB);
    unsigned short* Qbf = (unsigned short*)(ws + 28 * MB);
    unsigned char* msym = (unsigned char*)(ws + 36 * MB);
    float* linv = (float*)(ws + 24 * MB);                    // alias: Wt dead after gemm

    prep_kernel<<<8192, 256, 0, stream>>>(mask, x, Wq, Wk, msym, xbf, Wt);
    gemm_mfma_kernel<<<512, 256, 0, stream>>>(xbf, Wt, P2, 2048);
    ln2_kernel<<<8192, 256, 0, stream>>>(P2, bq, gq, bq_n, bk, gk, bk_n, Qbf, Kbf);
    attn_l_kernel<<<1024, 256, 0, stream>>>(Qbf, Kbf, msym, linv);
    attn_o_kernel<<<1024, 256, 0, stream>>>(Qbf, Kbf, msym, linv, out);
  } else {
    // split layout (32 MB): P bf16 [4096][1024] @0 (8), xbf @8 (8, Kbf aliases),
    // Wt @16 (4), Qbf @20 (8), msym @28 (4); linv aliases Wt (dead after 2nd gemm)
    unsigned short* P = (unsigned short*)ws;
    unsigned short* xbf = (unsigned short*)(ws + 8 * MB);
    unsigned short* Kbf = (unsigned short*)(ws + 8 * MB);    // alias: xbf dead after 2nd gemm
    unsigned short* Wt = (unsigned short*)(ws + 16 * MB);
    unsigned short* Qbf = (unsigned short*)(ws + 20 * MB);
    unsigned char* msym = (unsigned char*)(ws + 28 * MB);
    float* linv = (float*)(ws + 16 * MB);                    // alias: Wt dead after 2nd gemm

    prep_kernel<<<8192, 256, 0, stream>>>(mask, x, Wq, Wk, msym, xbf, Wt);
    gemm_mfma_kernel<<<256, 256, 0, stream>>>(xbf, Wt, P, 1024);
    ln_relu_bf_kernel<<<4096, 256, 0, stream>>>(P, 1024, 0, bq, gq, bq_n, Qbf);
    gemm_mfma_kernel<<<256, 256, 0, stream>>>(xbf, Wt + (size_t)1024 * 1024, P, 1024);
    ln_relu_bf_kernel<<<4096, 256, 0, stream>>>(P, 1024, 0, bk, gk, bk_n, Kbf);
    attn_l_kernel<<<1024, 256, 0, stream>>>(Qbf, Kbf, msym, linv);
    attn_o_kernel<<<1024, 256, 0, stream>>>(Qbf, Kbf, msym, linv, out);
  }
}

// Round 8
// 196.399 us; speedup vs baseline: 1.4277x; 1.4277x over previous
//
#include <hip/hip_runtime.h>
#include <hip/hip_bf16.h>

#define B_ 4
#define S_ 1024
#define E_ 1024
#define H_ 16
#define D_ 64

typedef __attribute__((ext_vector_type(8))) short short8;
typedef __attribute__((ext_vector_type(4))) float f32x4;

static __device__ __forceinline__ unsigned short f2bf(float x) {
  unsigned int u = __float_as_uint(x);
  unsigned int r = u + 0x7fffu + ((u >> 16) & 1u);  // round-to-nearest-even
  return (unsigned short)(r >> 16);
}
static __device__ __forceinline__ float bf2f(unsigned short b) {
  return __uint_as_float((unsigned int)b << 16);
}

#define GL2LDS16(g, l)                                                            \
  __builtin_amdgcn_global_load_lds(                                               \
      (const __attribute__((address_space(1))) unsigned int*)(g),                 \
      (__attribute__((address_space(3))) unsigned int*)(l), 16, 0, 0)

// gfx9 s_waitcnt imm: vmcnt[3:0]|[15:14], expcnt[6:4], lgkmcnt[11:8].
#define WAIT_VMCNT2() __builtin_amdgcn_s_waitcnt(0x0F72)
#define WAIT_VMCNT0() __builtin_amdgcn_s_waitcnt(0x0F70)

// Raw barrier WITHOUT the vmcnt(0) drain __syncthreads would emit.
// Legal: K staging is wave-private; only the l_lds exchange needs visibility.
#define BARRIER_LGKM()                                      \
  do {                                                      \
    asm volatile("s_waitcnt lgkmcnt(0)" ::: "memory");      \
    __builtin_amdgcn_s_barrier();                           \
  } while (0)

// combined scale: (1/sqrt(D)) * log2(e) applied in-register to the MFMA score,
// so exp() is a single v_exp_f32 (2^x). Q/K stored UNSCALED.
#define QSCALE 0.18033688011112042f
#define SCLAMP 115.41560327111707f  // 80 * log2(e)

// 16-lane sum via DPP (no LDS pipe): xor1, xor2, half-mirror, row-mirror.
static __device__ __forceinline__ float dpp_red16(float v) {
  v += __int_as_float(__builtin_amdgcn_update_dpp(0, __float_as_int(v), 0xB1, 0xF, 0xF, true));   // quad_perm [1,0,3,2]
  v += __int_as_float(__builtin_amdgcn_update_dpp(0, __float_as_int(v), 0x4E, 0xF, 0xF, true));   // quad_perm [2,3,0,1]
  v += __int_as_float(__builtin_amdgcn_update_dpp(0, __float_as_int(v), 0x141, 0xF, 0xF, true));  // row_half_mirror
  v += __int_as_float(__builtin_amdgcn_update_dpp(0, __float_as_int(v), 0x140, 0xF, 0xF, true));  // row_mirror
  return v;
}

// ---------- fused preprocessing: mask|mask^T, x->bf16, W->Wt bf16 ----------
// blocks 0..4095: mask_sym; 4096..6143: cvt_x; 6144..8191: wt transpose
__global__ __launch_bounds__(256) void prep_kernel(const int* __restrict__ mask,
                                                   const float* __restrict__ x,
                                                   const float* __restrict__ Wq,
                                                   const float* __restrict__ Wk,
                                                   unsigned char* __restrict__ msym,
                                                   unsigned short* __restrict__ xbf,
                                                   unsigned short* __restrict__ Wt) {
  __shared__ __align__(16) char u_lds[32 * 33 * 4];
  const int blk = blockIdx.x;
  const int tid = threadIdx.x;
  if (blk < 4096) {
    int (*T)[33] = (int(*)[33])u_lds;
    const int b = blk >> 10;
    const int rest = blk & 1023;
    const int i0 = (rest >> 5) << 5;
    const int j0 = (rest & 31) << 5;
    const int ii = tid >> 3;
    const int jj4 = (tid & 7) << 2;
    const size_t bO = (size_t)b * S_ * S_;
    const int4 m2 = *(const int4*)&mask[bO + (size_t)(j0 + ii) * S_ + i0 + jj4];
    T[ii][jj4 + 0] = m2.x; T[ii][jj4 + 1] = m2.y; T[ii][jj4 + 2] = m2.z; T[ii][jj4 + 3] = m2.w;
    __syncthreads();
    const int4 m1 = *(const int4*)&mask[bO + (size_t)(i0 + ii) * S_ + j0 + jj4];
    uchar4 o;
    o.x = ((m1.x != 0) || (T[jj4 + 0][ii] != 0)) ? 1 : 0;
    o.y = ((m1.y != 0) || (T[jj4 + 1][ii] != 0)) ? 1 : 0;
    o.z = ((m1.z != 0) || (T[jj4 + 2][ii] != 0)) ? 1 : 0;
    o.w = ((m1.w != 0) || (T[jj4 + 3][ii] != 0)) ? 1 : 0;
    *(uchar4*)&msym[bO + (size_t)(i0 + ii) * S_ + j0 + jj4] = o;
  } else if (blk < 6144) {
    const size_t i = ((size_t)(blk - 4096) * 256 + tid) * 8;
    const float4 a = *(const float4*)(x + i);
    const float4 b = *(const float4*)(x + i + 4);
    const ushort4 p0 = {f2bf(a.x), f2bf(a.y), f2bf(a.z), f2bf(a.w)};
    const ushort4 p1 = {f2bf(b.x), f2bf(b.y), f2bf(b.z), f2bf(b.w)};
    *(ushort4*)(xbf + i) = p0;
    *(ushort4*)(xbf + i + 4) = p1;
  } else {
    unsigned short (*T2)[36] = (unsigned short(*)[36])u_lds;
    const int wblk = blk - 6144;           // 2 * 32 * 32
    const int mat = wblk >> 10;
    const int kt = (wblk >> 5) & 31, ntb = wblk & 31;
    const float* W = mat ? Wk : Wq;
    const int r = tid >> 3, c4 = (tid & 7) << 2;
    const float4 v = *(const float4*)&W[(size_t)(kt * 32 + r) * 1024 + ntb * 32 + c4];
    T2[r][c4 + 0] = f2bf(v.x); T2[r][c4 + 1] = f2bf(v.y);
    T2[r][c4 + 2] = f2bf(v.z); T2[r][c4 + 3] = f2bf(v.w);
    __syncthreads();
    const ushort4 o = {T2[c4 + 0][r], T2[c4 + 1][r], T2[c4 + 2][r], T2[c4 + 3][r]};
    *(ushort4*)&Wt[(size_t)(mat * 1024 + ntb * 32 + r) * 1024 + kt * 32 + c4] = o;
  }
}

// ------- bf16 MFMA GEMM, BK=64: P[4096][nstride] = xbf[4096][1024] @ Wt^T --------
__global__ __launch_bounds__(256) void gemm_mfma_kernel(const unsigned short* __restrict__ Abf,
                                                        const unsigned short* __restrict__ Wt,
                                                        unsigned short* __restrict__ P,
                                                        int nstride) {
  __shared__ __align__(16) unsigned short As[128 * 64];  // 16 KB, [m][k]
  __shared__ __align__(16) unsigned short Bs[128 * 64];  // 16 KB, [n][k]
  const int tid = threadIdx.x;
  const int m0 = (blockIdx.x & 31) << 7;
  const int n0 = (blockIdx.x >> 5) << 7;
  const int wave = tid >> 6, lane = tid & 63;
  const int ln15 = lane & 15, rg = lane >> 4;
  const int wm = (wave & 1) << 6;
  const int wn = (wave >> 1) << 6;
  const int sr = tid >> 3;
  const int sc = (tid & 7) << 3;
  const unsigned short* gA = Abf + (size_t)(m0 + sr) * 1024 + sc;
  const unsigned short* gB = Wt + (size_t)(n0 + sr) * 1024 + sc;
  unsigned short* lA = As + tid * 8;
  unsigned short* lB = Bs + tid * 8;
  f32x4 acc[4][4];
#pragma unroll
  for (int i = 0; i < 4; ++i)
#pragma unroll
    for (int j = 0; j < 4; ++j) acc[i][j] = (f32x4){0.0f, 0.0f, 0.0f, 0.0f};

  const unsigned short* pa = As + (wm + ln15) * 64 + rg * 8;
  const unsigned short* pb = Bs + (wn + ln15) * 64 + rg * 8;
  for (int k0 = 0; k0 < E_; k0 += 64) {
#pragma unroll
    for (int j = 0; j < 4; ++j) {
      GL2LDS16(gA + k0 + (size_t)(j * 32) * 1024, lA + j * 2048);
      GL2LDS16(gB + k0 + (size_t)(j * 32) * 1024, lB + j * 2048);
    }
    __syncthreads();
#pragma unroll
    for (int kk = 0; kk < 2; ++kk) {
      short8 af[4], bfr[4];
#pragma unroll
      for (int i = 0; i < 4; ++i) af[i] = *(const short8*)(pa + i * 16 * 64 + kk * 32);
#pragma unroll
      for (int j = 0; j < 4; ++j) bfr[j] = *(const short8*)(pb + j * 16 * 64 + kk * 32);
#pragma unroll
      for (int i = 0; i < 4; ++i)
#pragma unroll
        for (int j = 0; j < 4; ++j)
          acc[i][j] = __builtin_amdgcn_mfma_f32_16x16x32_bf16(af[i], bfr[j], acc[i][j], 0, 0, 0);
    }
    __syncthreads();
  }
#pragma unroll
  for (int i = 0; i < 4; ++i)
#pragma unroll
    for (int j = 0; j < 4; ++j)
#pragma unroll
      for (int r = 0; r < 4; ++r) {
        const int row = m0 + wm + i * 16 + rg * 4 + r;
        const int col = n0 + wn + j * 16 + ln15;
        P[(size_t)row * nstride + col] = f2bf(acc[i][j][r]);
      }
}

// ---- bias+LN+ReLU from bf16 P; emit bf16 head-major [b*16+h][s][d] ----
__device__ __forceinline__ void ln_body(const unsigned short* p, const float* bias,
                                        const float* gamma, const float* beta,
                                        unsigned short* obf, int b, int s, int tid) {
  const ushort4 pv = *(const ushort4*)(p + tid * 4);
  float4 v = {bf2f(pv.x), bf2f(pv.y), bf2f(pv.z), bf2f(pv.w)};
  const float4 bb = ((const float4*)bias)[tid];
  v.x += bb.x; v.y += bb.y; v.z += bb.z; v.w += bb.w;
  float sum = v.x + v.y + v.z + v.w;
  float s2 = v.x * v.x + v.y * v.y + v.z * v.z + v.w * v.w;
#pragma unroll
  for (int off = 32; off >= 1; off >>= 1) {
    sum += __shfl_xor(sum, off);
    s2 += __shfl_xor(s2, off);
  }
  __shared__ float red[2][4];
  const int wave = tid >> 6, lane = tid & 63;
  if (lane == 0) { red[0][wave] = sum; red[1][wave] = s2; }
  __syncthreads();
  sum = red[0][0] + red[0][1] + red[0][2] + red[0][3];
  s2 = red[1][0] + red[1][1] + red[1][2] + red[1][3];
  const float mu = sum * (1.0f / E_);
  const float var = s2 * (1.0f / E_) - mu * mu;
  const float r = rsqrtf(var + 1e-5f);
  const float4 g = ((const float4*)gamma)[tid];
  const float4 bt = ((const float4*)beta)[tid];
  const float o0 = fmaxf((v.x - mu) * r * g.x + bt.x, 0.0f);
  const float o1 = fmaxf((v.y - mu) * r * g.y + bt.y, 0.0f);
  const float o2 = fmaxf((v.z - mu) * r * g.z + bt.z, 0.0f);
  const float o3 = fmaxf((v.w - mu) * r * g.w + bt.w, 0.0f);
  const int h = tid >> 4;
  const int d = (tid & 15) << 2;
  const ushort4 ob = {f2bf(o0), f2bf(o1), f2bf(o2), f2bf(o3)};
  *(ushort4*)&obf[((size_t)(b * H_ + h) * S_ + s) * D_ + d] = ob;
}

__global__ __launch_bounds__(256) void ln_relu_bf_kernel(const unsigned short* __restrict__ P,
                                                         int rowstride, int coloff,
                                                         const float* __restrict__ bias,
                                                         const float* __restrict__ gamma,
                                                         const float* __restrict__ beta,
                                                         unsigned short* __restrict__ obf) {
  const int row = blockIdx.x;
  ln_body(P + (size_t)row * rowstride + coloff, bias, gamma, beta, obf,
          row >> 10, row & 1023, threadIdx.x);
}

// fused both-LN launch (40MB path): blocks 0..4095 -> Q, 4096..8191 -> K
__global__ __launch_bounds__(256) void ln2_kernel(const unsigned short* __restrict__ P2,
                                                  const float* __restrict__ bq,
                                                  const float* __restrict__ gq,
                                                  const float* __restrict__ bqn,
                                                  const float* __restrict__ bk,
                                                  const float* __restrict__ gk,
                                                  const float* __restrict__ bkn,
                                                  unsigned short* __restrict__ Qbf,
                                                  unsigned short* __restrict__ Kbf) {
  const int blk = blockIdx.x;
  const int sel = blk >> 12;
  const int row = blk & 4095;
  ln_body(P2 + (size_t)row * 2048 + sel * 1024,
          sel ? bk : bq, sel ? gk : gq, sel ? bkn : bqn,
          sel ? Kbf : Qbf, row >> 10, row & 1023, threadIdx.x);
}

// ======= attention v17: v15 staging pipeline + head-split for 2 blocks/CU =======
// v15's limiter: 16 waves in lockstep behind 1 barrier/head at 1 block/CU
// (LDS 133 KB) - nothing to run while waves queue at the barrier. v17 halves
// the staging tile (16 keys/step, Ks[2][16][1024] = 64 KB -> ~67 KB total) so
// TWO blocks fit per CU, and splits the head loop across blocks (grid 512 =
// b x qt x head-half; each block sums 8 heads). Both halves accumulate into
// the zeroed output via HW fp32 atomics (exactly 2 adds/element; float add is
// commutative -> bit-deterministic). The v15 XOR-swizzle read formulas are
// invariant under the 16-key tile split (chunk c = key_local>>3 folds into
// ln15*64). vmcnt: 2-op batches -> vmcnt(2); last local step drains 0.
// Mask uses direct mbits tests (not mf[] floats) to hold VGPR <= 64 for
// 8 waves/SIMD. Raw lgkm-only barrier (v15) kept: staging stays wave-private.
__global__ __launch_bounds__(1024, 8) void attn17_kernel(const unsigned short* __restrict__ Qbf,
                                                         const unsigned short* __restrict__ Kbf,
                                                         const unsigned char* __restrict__ msym,
                                                         float* __restrict__ out) {
  __shared__ __align__(16) unsigned short Ks[2][16][1024];  // [par][wave][16 keys x 64] 64 KB
  __shared__ __align__(16) float l_lds[2][16][20];          // [head-par][wave][q pad20] 2.5 KB
  const int tid = threadIdx.x;
  const int wave = tid >> 6, lane = tid & 63;
  const int ln15 = lane & 15, rg = lane >> 4;
  const int b = blockIdx.x & 3;                 // XCD swizzle: K[b] L2-resident
  const int q0 = ((blockIdx.x >> 2) & 63) << 4;
  const int h0 = (blockIdx.x >> 8) << 3;        // head-half: 0 or 8
  const unsigned short* Kb = Kbf + (size_t)(b * H_ + h0) * S_ * D_;
  const unsigned short* Qb = Qbf + (size_t)(b * H_ + h0) * S_ * D_;

  // mask bits: bit(hf*8 + jt*4 + r) = msym[q0+rg*4+r][hf*512 + wave*32 + jt*16 + ln15]
  // (heads share the mask; tested directly per element to save 16 VGPRs)
  unsigned int mbits = 0;
#pragma unroll
  for (int hf = 0; hf < 2; ++hf)
#pragma unroll
    for (int jt = 0; jt < 2; ++jt)
#pragma unroll
      for (int r = 0; r < 4; ++r)
        mbits |= (msym[((size_t)b * S_ + q0 + rg * 4 + r) * S_ + hf * 512 + wave * 32 + jt * 16 + ln15]
                      ? 1u : 0u) << (hf * 8 + jt * 4 + r);

  // DMA lane mapping (shorts) for a 16-key (2 KB) tile: key_local = c*8+(lane>>3),
  // chunk = (lane&7)^(lane>>3) [XOR swizzle], c in {0,1}.
  const int gl = ((lane >> 3) << 6) + (((lane & 7) ^ (lane >> 3)) << 3);
  const unsigned short* gwave = Kb + wave * 2048 + gl;
  // step s (0..31): head h = s>>2, half = (s>>1)&1, subhalf = s&1
  // global offset(shorts) = (s>>2)*65536 + ((s>>1)&1)*32768 + (s&1)*1024
  // prologue: batch 0 into Ks[0]
  GL2LDS16(gwave, &Ks[0][wave][0]);
  GL2LDS16(gwave + 512, &Ks[0][wave][512]);

  const int pfrag = (rg ^ (ln15 & 7)) * 8;  // swizzled chunk offset (shorts)
  float o[2][2][4] = {};
  float ef[2][2][4];
  float la[4];

#pragma unroll 1
  for (int h = 0; h < 8; ++h) {
    // A-frags from global: same 2KB for all 16 waves -> L1 broadcast
    const unsigned short* qrow = Qb + ((size_t)h * S_ + q0 + ln15) * D_ + rg * 8;
    const short8 a0 = *(const short8*)qrow;
    const short8 a1 = *(const short8*)(qrow + 32);
    la[0] = la[1] = la[2] = la[3] = 0.0f;
#pragma unroll
    for (int sub = 0; sub < 4; ++sub) {
      const int s = h * 4 + sub;
      if (s < 31) {
        const int s1 = s + 1;
        const unsigned short* g = gwave + (size_t)(s1 >> 2) * 65536 +
                                  (size_t)((s1 >> 1) & 1) * 32768 + (s1 & 1) * 1024;
        unsigned short* lp = &Ks[s1 & 1][wave][0];
        GL2LDS16(g, lp);
        GL2LDS16(g + 512, lp + 512);
        WAIT_VMCNT2();
      } else {
        WAIT_VMCNT0();  // nothing issued after the last batch: full drain
      }
      const unsigned short* kw = &Ks[s & 1][wave][ln15 * 64];
      const short8 b0 = *(const short8*)(kw + pfrag);
      const short8 b1 = *(const short8*)(kw + (pfrag ^ 32));
      f32x4 cc = {0.0f, 0.0f, 0.0f, 0.0f};
      cc = __builtin_amdgcn_mfma_f32_16x16x32_bf16(a0, b0, cc, 0, 0, 0);
      cc = __builtin_amdgcn_mfma_f32_16x16x32_bf16(a1, b1, cc, 0, 0, 0);
#pragma unroll
      for (int r = 0; r < 4; ++r) {
        const float sv = fminf(cc[r] * QSCALE, SCLAMP);
        const float e2 = __builtin_amdgcn_exp2f(sv);
        const float ev = (mbits & (1u << ((sub >> 1) * 8 + (sub & 1) * 4 + r))) ? 0.0f : e2;
        ef[sub >> 1][sub & 1][r] = ev;
        la[r] += ev;
      }
    }
    // wave-local l: DPP butterfly over the 16 key-lanes per q-row
#pragma unroll
    for (int r = 0; r < 4; ++r) la[r] = dpp_red16(la[r]);
    if (ln15 == 0) *(f32x4*)&l_lds[h & 1][wave][rg * 4] = (f32x4){la[0], la[1], la[2], la[3]};
    BARRIER_LGKM();  // ONE raw barrier per head: l exchange only, DMAs stay in flight
    // cross-wave reduce without a second barrier: lane reads wave-ln15's partial
    const f32x4 pw = *(const f32x4*)&l_lds[h & 1][ln15][rg * 4];
#pragma unroll
    for (int r = 0; r < 4; ++r) {
      const float li = __builtin_amdgcn_rcpf(dpp_red16(pw[r]));
#pragma unroll
      for (int hf = 0; hf < 2; ++hf)
#pragma unroll
        for (int jt = 0; jt < 2; ++jt) o[hf][jt][r] += ef[hf][jt][r] * li;
    }
  }
  // accumulate into zeroed out: HW fp32 atomic add, 2 contributions/element,
  // bit-deterministic (float add commutes). 64B contiguous per (hf,jt,r).
#pragma unroll
  for (int hf = 0; hf < 2; ++hf)
#pragma unroll
    for (int jt = 0; jt < 2; ++jt)
#pragma unroll
      for (int r = 0; r < 4; ++r)
        unsafeAtomicAdd(&out[((size_t)b * S_ + q0 + rg * 4 + r) * S_ +
                             hf * 512 + wave * 32 + jt * 16 + ln15],
                        o[hf][jt][r] * 0.0625f);
}

extern "C" void kernel_launch(void* const* d_in, const int* in_sizes, int n_in,
                              void* d_out, int out_size, void* d_ws, size_t ws_size,
                              hipStream_t stream) {
  const float* x = (const float*)d_in[0];
  const int* mask = (const int*)d_in[1];
  const float* Wq = (const float*)d_in[2];
  const float* bq = (const float*)d_in[3];
  const float* Wk = (const float*)d_in[4];
  const float* bk = (const float*)d_in[5];
  const float* gq = (const float*)d_in[6];
  const float* bq_n = (const float*)d_in[7];
  const float* gk = (const float*)d_in[8];
  const float* bk_n = (const float*)d_in[9];
  float* out = (float*)d_out;

  char* ws = (char*)d_ws;
  const size_t MB = 1024 * 1024;

  if (ws_size >= 40 * MB) {
    // fused layout (40 MB): P2 bf16 [4096][2048] @0 (16), xbf @16 (8, Kbf aliases),
    // Wt @24 (4), Qbf @28 (8), msym @36 (4)
    unsigned short* P2 = (unsigned short*)ws;
    unsigned short* xbf = (unsigned short*)(ws + 16 * MB);
    unsigned short* Kbf = (unsigned short*)(ws + 16 * MB);   // alias: xbf dead after gemm
    unsigned short* Wt = (unsigned short*)(ws + 24 * MB);
    unsigned short* Qbf = (unsigned short*)(ws + 28 * MB);
    unsigned char* msym = (unsigned char*)(ws + 36 * MB);

    prep_kernel<<<8192, 256, 0, stream>>>(mask, x, Wq, Wk, msym, xbf, Wt);
    gemm_mfma_kernel<<<512, 256, 0, stream>>>(xbf, Wt, P2, 2048);
    ln2_kernel<<<8192, 256, 0, stream>>>(P2, bq, gq, bq_n, bk, gk, bk_n, Qbf, Kbf);
    attn17_kernel<<<512, 1024, 0, stream>>>(Qbf, Kbf, msym, out);
  } else {
    // split layout (32 MB): P bf16 [4096][1024] @0 (8), xbf @8 (8, Kbf aliases),
    // Wt @16 (4), Qbf @20 (8), msym @28 (4)
    unsigned short* P = (unsigned short*)ws;
    unsigned short* xbf = (unsigned short*)(ws + 8 * MB);
    unsigned short* Kbf = (unsigned short*)(ws + 8 * MB);    // alias: xbf dead after 2nd gemm
    unsigned short* Wt = (unsigned short*)(ws + 16 * MB);
    unsigned short* Qbf = (unsigned short*)(ws + 20 * MB);
    unsigned char* msym = (unsigned char*)(ws + 28 * MB);

    prep_kernel<<<8192, 256, 0, stream>>>(mask, x, Wq, Wk, msym, xbf, Wt);
    gemm_mfma_kernel<<<256, 256, 0, stream>>>(xbf, Wt, P, 1024);
    ln_relu_bf_kernel<<<4096, 256, 0, stream>>>(P, 1024, 0, bq, gq, bq_n, Qbf);
    gemm_mfma_kernel<<<256, 256, 0, stream>>>(xbf, Wt + (size_t)1024 * 1024, P, 1024);
    ln_relu_bf_kernel<<<4096, 256, 0, stream>>>(P, 1024, 0, bk, gk, bk_n, Kbf);
    attn17_kernel<<<512, 1024, 0, stream>>>(Qbf, Kbf, msym, out);
  }
}

// Round 9
// 192.193 us; speedup vs baseline: 1.4589x; 1.0219x over previous
//
#include <hip/hip_runtime.h>
#include <hip/hip_bf16.h>

#define B_ 4
#define S_ 1024
#define E_ 1024
#define H_ 16
#define D_ 64

typedef __attribute__((ext_vector_type(8))) short short8;
typedef __attribute__((ext_vector_type(4))) float f32x4;

static __device__ __forceinline__ unsigned short f2bf(float x) {
  unsigned int u = __float_as_uint(x);
  unsigned int r = u + 0x7fffu + ((u >> 16) & 1u);  // round-to-nearest-even
  return (unsigned short)(r >> 16);
}
static __device__ __forceinline__ float bf2f(unsigned short b) {
  return __uint_as_float((unsigned int)b << 16);
}

#define GL2LDS16(g, l)                                                            \
  __builtin_amdgcn_global_load_lds(                                               \
      (const __attribute__((address_space(1))) unsigned int*)(g),                 \
      (__attribute__((address_space(3))) unsigned int*)(l), 16, 0, 0)

// gfx9 s_waitcnt imm: vmcnt[3:0]|[15:14], expcnt[6:4], lgkmcnt[11:8].
#define WAIT_VMCNT4() __builtin_amdgcn_s_waitcnt(0x0F74)
#define WAIT_VMCNT0() __builtin_amdgcn_s_waitcnt(0x0F70)

// Raw barrier WITHOUT the vmcnt(0) drain __syncthreads would emit.
// Legal: K staging is wave-private; only the l_lds exchange needs visibility.
#define BARRIER_LGKM()                                      \
  do {                                                      \
    asm volatile("s_waitcnt lgkmcnt(0)" ::: "memory");      \
    __builtin_amdgcn_s_barrier();                           \
  } while (0)

// combined scale: (1/sqrt(D)) * log2(e) applied in-register to the MFMA score,
// so exp() is a single v_exp_f32 (2^x). Q/K stored UNSCALED.
#define QSCALE 0.18033688011112042f
#define SCLAMP 115.41560327111707f  // 80 * log2(e)

// 16-lane sum via DPP: xor1, xor2, half-mirror, row-mirror.
static __device__ __forceinline__ float dpp_red16(float v) {
  v += __int_as_float(__builtin_amdgcn_update_dpp(0, __float_as_int(v), 0xB1, 0xF, 0xF, true));   // quad_perm [1,0,3,2]
  v += __int_as_float(__builtin_amdgcn_update_dpp(0, __float_as_int(v), 0x4E, 0xF, 0xF, true));   // quad_perm [2,3,0,1]
  v += __int_as_float(__builtin_amdgcn_update_dpp(0, __float_as_int(v), 0x141, 0xF, 0xF, true));  // row_half_mirror
  v += __int_as_float(__builtin_amdgcn_update_dpp(0, __float_as_int(v), 0x140, 0xF, 0xF, true));  // row_mirror
  return v;
}
// 8-lane sum via DPP (groups of 8): xor1, xor2, xor4.
static __device__ __forceinline__ float dpp_red8(float v) {
  v += __int_as_float(__builtin_amdgcn_update_dpp(0, __float_as_int(v), 0xB1, 0xF, 0xF, true));   // quad_perm [1,0,3,2]
  v += __int_as_float(__builtin_amdgcn_update_dpp(0, __float_as_int(v), 0x4E, 0xF, 0xF, true));   // quad_perm [2,3,0,1]
  v += __int_as_float(__builtin_amdgcn_update_dpp(0, __float_as_int(v), 0x141, 0xF, 0xF, true));  // row_half_mirror
  return v;
}

// ---------- fused preprocessing: mask|mask^T, x->bf16, W->Wt bf16 ----------
// blocks 0..4095: mask_sym; 4096..6143: cvt_x; 6144..8191: wt transpose
__global__ __launch_bounds__(256) void prep_kernel(const int* __restrict__ mask,
                                                   const float* __restrict__ x,
                                                   const float* __restrict__ Wq,
                                                   const float* __restrict__ Wk,
                                                   unsigned char* __restrict__ msym,
                                                   unsigned short* __restrict__ xbf,
                                                   unsigned short* __restrict__ Wt) {
  __shared__ __align__(16) char u_lds[32 * 33 * 4];
  const int blk = blockIdx.x;
  const int tid = threadIdx.x;
  if (blk < 4096) {
    int (*T)[33] = (int(*)[33])u_lds;
    const int b = blk >> 10;
    const int rest = blk & 1023;
    const int i0 = (rest >> 5) << 5;
    const int j0 = (rest & 31) << 5;
    const int ii = tid >> 3;
    const int jj4 = (tid & 7) << 2;
    const size_t bO = (size_t)b * S_ * S_;
    const int4 m2 = *(const int4*)&mask[bO + (size_t)(j0 + ii) * S_ + i0 + jj4];
    T[ii][jj4 + 0] = m2.x; T[ii][jj4 + 1] = m2.y; T[ii][jj4 + 2] = m2.z; T[ii][jj4 + 3] = m2.w;
    __syncthreads();
    const int4 m1 = *(const int4*)&mask[bO + (size_t)(i0 + ii) * S_ + j0 + jj4];
    uchar4 o;
    o.x = ((m1.x != 0) || (T[jj4 + 0][ii] != 0)) ? 1 : 0;
    o.y = ((m1.y != 0) || (T[jj4 + 1][ii] != 0)) ? 1 : 0;
    o.z = ((m1.z != 0) || (T[jj4 + 2][ii] != 0)) ? 1 : 0;
    o.w = ((m1.w != 0) || (T[jj4 + 3][ii] != 0)) ? 1 : 0;
    *(uchar4*)&msym[bO + (size_t)(i0 + ii) * S_ + j0 + jj4] = o;
  } else if (blk < 6144) {
    const size_t i = ((size_t)(blk - 4096) * 256 + tid) * 8;
    const float4 a = *(const float4*)(x + i);
    const float4 b = *(const float4*)(x + i + 4);
    const ushort4 p0 = {f2bf(a.x), f2bf(a.y), f2bf(a.z), f2bf(a.w)};
    const ushort4 p1 = {f2bf(b.x), f2bf(b.y), f2bf(b.z), f2bf(b.w)};
    *(ushort4*)(xbf + i) = p0;
    *(ushort4*)(xbf + i + 4) = p1;
  } else {
    unsigned short (*T2)[36] = (unsigned short(*)[36])u_lds;
    const int wblk = blk - 6144;           // 2 * 32 * 32
    const int mat = wblk >> 10;
    const int kt = (wblk >> 5) & 31, ntb = wblk & 31;
    const float* W = mat ? Wk : Wq;
    const int r = tid >> 3, c4 = (tid & 7) << 2;
    const float4 v = *(const float4*)&W[(size_t)(kt * 32 + r) * 1024 + ntb * 32 + c4];
    T2[r][c4 + 0] = f2bf(v.x); T2[r][c4 + 1] = f2bf(v.y);
    T2[r][c4 + 2] = f2bf(v.z); T2[r][c4 + 3] = f2bf(v.w);
    __syncthreads();
    const ushort4 o = {T2[c4 + 0][r], T2[c4 + 1][r], T2[c4 + 2][r], T2[c4 + 3][r]};
    *(ushort4*)&Wt[(size_t)(mat * 1024 + ntb * 32 + r) * 1024 + kt * 32 + c4] = o;
  }
}

// ------- bf16 MFMA GEMM, BK=64: P[4096][nstride] = xbf[4096][1024] @ Wt^T --------
__global__ __launch_bounds__(256) void gemm_mfma_kernel(const unsigned short* __restrict__ Abf,
                                                        const unsigned short* __restrict__ Wt,
                                                        unsigned short* __restrict__ P,
                                                        int nstride) {
  __shared__ __align__(16) unsigned short As[128 * 64];  // 16 KB, [m][k]
  __shared__ __align__(16) unsigned short Bs[128 * 64];  // 16 KB, [n][k]
  const int tid = threadIdx.x;
  const int m0 = (blockIdx.x & 31) << 7;
  const int n0 = (blockIdx.x >> 5) << 7;
  const int wave = tid >> 6, lane = tid & 63;
  const int ln15 = lane & 15, rg = lane >> 4;
  const int wm = (wave & 1) << 6;
  const int wn = (wave >> 1) << 6;
  const int sr = tid >> 3;
  const int sc = (tid & 7) << 3;
  const unsigned short* gA = Abf + (size_t)(m0 + sr) * 1024 + sc;
  const unsigned short* gB = Wt + (size_t)(n0 + sr) * 1024 + sc;
  unsigned short* lA = As + tid * 8;
  unsigned short* lB = Bs + tid * 8;
  f32x4 acc[4][4];
#pragma unroll
  for (int i = 0; i < 4; ++i)
#pragma unroll
    for (int j = 0; j < 4; ++j) acc[i][j] = (f32x4){0.0f, 0.0f, 0.0f, 0.0f};

  const unsigned short* pa = As + (wm + ln15) * 64 + rg * 8;
  const unsigned short* pb = Bs + (wn + ln15) * 64 + rg * 8;
  for (int k0 = 0; k0 < E_; k0 += 64) {
#pragma unroll
    for (int j = 0; j < 4; ++j) {
      GL2LDS16(gA + k0 + (size_t)(j * 32) * 1024, lA + j * 2048);
      GL2LDS16(gB + k0 + (size_t)(j * 32) * 1024, lB + j * 2048);
    }
    __syncthreads();
#pragma unroll
    for (int kk = 0; kk < 2; ++kk) {
      short8 af[4], bfr[4];
#pragma unroll
      for (int i = 0; i < 4; ++i) af[i] = *(const short8*)(pa + i * 16 * 64 + kk * 32);
#pragma unroll
      for (int j = 0; j < 4; ++j) bfr[j] = *(const short8*)(pb + j * 16 * 64 + kk * 32);
#pragma unroll
      for (int i = 0; i < 4; ++i)
#pragma unroll
        for (int j = 0; j < 4; ++j)
          acc[i][j] = __builtin_amdgcn_mfma_f32_16x16x32_bf16(af[i], bfr[j], acc[i][j], 0, 0, 0);
    }
    __syncthreads();
  }
#pragma unroll
  for (int i = 0; i < 4; ++i)
#pragma unroll
    for (int j = 0; j < 4; ++j)
#pragma unroll
      for (int r = 0; r < 4; ++r) {
        const int row = m0 + wm + i * 16 + rg * 4 + r;
        const int col = n0 + wn + j * 16 + ln15;
        P[(size_t)row * nstride + col] = f2bf(acc[i][j][r]);
      }
}

// ---- bias+LN+ReLU from bf16 P; emit bf16 head-major [b*16+h][s][d] ----
__device__ __forceinline__ void ln_body(const unsigned short* p, const float* bias,
                                        const float* gamma, const float* beta,
                                        unsigned short* obf, int b, int s, int tid) {
  const ushort4 pv = *(const ushort4*)(p + tid * 4);
  float4 v = {bf2f(pv.x), bf2f(pv.y), bf2f(pv.z), bf2f(pv.w)};
  const float4 bb = ((const float4*)bias)[tid];
  v.x += bb.x; v.y += bb.y; v.z += bb.z; v.w += bb.w;
  float sum = v.x + v.y + v.z + v.w;
  float s2 = v.x * v.x + v.y * v.y + v.z * v.z + v.w * v.w;
#pragma unroll
  for (int off = 32; off >= 1; off >>= 1) {
    sum += __shfl_xor(sum, off);
    s2 += __shfl_xor(s2, off);
  }
  __shared__ float red[2][4];
  const int wave = tid >> 6, lane = tid & 63;
  if (lane == 0) { red[0][wave] = sum; red[1][wave] = s2; }
  __syncthreads();
  sum = red[0][0] + red[0][1] + red[0][2] + red[0][3];
  s2 = red[1][0] + red[1][1] + red[1][2] + red[1][3];
  const float mu = sum * (1.0f / E_);
  const float var = s2 * (1.0f / E_) - mu * mu;
  const float r = rsqrtf(var + 1e-5f);
  const float4 g = ((const float4*)gamma)[tid];
  const float4 bt = ((const float4*)beta)[tid];
  const float o0 = fmaxf((v.x - mu) * r * g.x + bt.x, 0.0f);
  const float o1 = fmaxf((v.y - mu) * r * g.y + bt.y, 0.0f);
  const float o2 = fmaxf((v.z - mu) * r * g.z + bt.z, 0.0f);
  const float o3 = fmaxf((v.w - mu) * r * g.w + bt.w, 0.0f);
  const int h = tid >> 4;
  const int d = (tid & 15) << 2;
  const ushort4 ob = {f2bf(o0), f2bf(o1), f2bf(o2), f2bf(o3)};
  *(ushort4*)&obf[((size_t)(b * H_ + h) * S_ + s) * D_ + d] = ob;
}

__global__ __launch_bounds__(256) void ln_relu_bf_kernel(const unsigned short* __restrict__ P,
                                                         int rowstride, int coloff,
                                                         const float* __restrict__ bias,
                                                         const float* __restrict__ gamma,
                                                         const float* __restrict__ beta,
                                                         unsigned short* __restrict__ obf) {
  const int row = blockIdx.x;
  ln_body(P + (size_t)row * rowstride + coloff, bias, gamma, beta, obf,
          row >> 10, row & 1023, threadIdx.x);
}

// fused both-LN launch (40MB path): blocks 0..4095 -> Q, 4096..8191 -> K
__global__ __launch_bounds__(256) void ln2_kernel(const unsigned short* __restrict__ P2,
                                                  const float* __restrict__ bq,
                                                  const float* __restrict__ gq,
                                                  const float* __restrict__ bqn,
                                                  const float* __restrict__ bk,
                                                  const float* __restrict__ gk,
                                                  const float* __restrict__ bkn,
                                                  unsigned short* __restrict__ Qbf,
                                                  unsigned short* __restrict__ Kbf) {
  const int blk = blockIdx.x;
  const int sel = blk >> 12;
  const int row = blk & 4095;
  ln_body(P2 + (size_t)row * 2048 + sel * 1024,
          sel ? bk : bq, sel ? gk : gq, sel ? bkn : bqn,
          sel ? Kbf : Qbf, row >> 10, row & 1023, threadIdx.x);
}

// ===== attention v18: v15 pipeline, 8-wave blocks, 2 blocks/CU, head-split =====
// v17 post-mortem: halving the staging step to 16 keys halved the work per
// vmcnt wait -> more exposed DMA latency; occupancy didn't compensate.
// v18 keeps v15's EXACT per-wave step (32-key tile, 4-op DMA batch, vmcnt(4),
// 4 MFMA + 32 exp per wait, raw lgkm barrier) and changes only organization:
// 512-thread blocks (8 waves), LDS 66.8 KB -> 2 independent blocks/CU (one
// runs while the other queues at its barrier), barrier domain halved to
// 8 waves, head loop split across blocks (grid 512 = b x qt x head-half),
// halves merged by HW fp32 atomics into the zeroed output (v17-verified).
// A head is 4 steps of 256 keys (8 waves x 32); XOR-swizzle algebra unchanged
// (global chunk = slot ^ (key&7) cancellation is per-wave-tile, tile size
// unchanged). mask: 32 bits (c,jt,r) exactly fills one unsigned.
__global__ __launch_bounds__(512, 4) void attn18_kernel(const unsigned short* __restrict__ Qbf,
                                                        const unsigned short* __restrict__ Kbf,
                                                        const unsigned char* __restrict__ msym,
                                                        float* __restrict__ out) {
  __shared__ __align__(16) unsigned short Ks[2][8][2048];  // [par][wave][32 keys x 64] 64 KB
  __shared__ __align__(16) float l_lds[2][8][20];          // [head-par][wave][q pad20] 1.3 KB
  const int tid = threadIdx.x;
  const int wave = tid >> 6, lane = tid & 63;               // wave 0..7
  const int ln15 = lane & 15, rg = lane >> 4;
  const int b = blockIdx.x & 3;                 // XCD swizzle: K[b] L2-resident
  const int q0 = ((blockIdx.x >> 2) & 63) << 4;
  const int h0 = (blockIdx.x >> 8) << 3;        // head-half: 0 or 8
  const unsigned short* Kb = Kbf + (size_t)(b * H_ + h0) * S_ * D_;
  const unsigned short* Qb = Qbf + (size_t)(b * H_ + h0) * S_ * D_;

  // mask bits: bit(c*8 + jt*4 + r) = msym[q0+rg*4+r][c*256 + wave*32 + jt*16 + ln15]
  unsigned int mbits = 0;
#pragma unroll
  for (int c = 0; c < 4; ++c)
#pragma unroll
    for (int jt = 0; jt < 2; ++jt)
#pragma unroll
      for (int r = 0; r < 4; ++r)
        mbits |= (msym[((size_t)b * S_ + q0 + rg * 4 + r) * S_ + c * 256 + wave * 32 + jt * 16 + ln15]
                      ? 1u : 0u) << (c * 8 + jt * 4 + r);

  // DMA lane mapping (shorts): key_local = i*8 + (lane>>3), phys slot = lane&7,
  // global chunk = (lane&7) ^ (lane>>3)  [XOR swizzle]
  const int gl = ((lane >> 3) << 6) + (((lane & 7) ^ (lane >> 3)) << 3);
  const unsigned short* gwave = Kb + wave * 2048 + gl;
  // step s (0..31): head h = s>>2, chunk c = s&3;
  // global offset(shorts) = (s>>2)*65536 + (s&3)*16384
  // prologue: batch 0 into Ks[0]
#pragma unroll
  for (int c = 0; c < 4; ++c) GL2LDS16(gwave + c * 512, &Ks[0][wave][c * 512]);

  const int pfrag = (rg ^ (ln15 & 7)) * 8;  // swizzled chunk offset (shorts)
  float o[4][2][4] = {};
  float ef[4][2][4];
  float la[4];

#pragma unroll 1
  for (int h = 0; h < 8; ++h) {
    // A-frags from global: same 2KB for all 8 waves -> L1 broadcast
    const unsigned short* qrow = Qb + ((size_t)h * S_ + q0 + ln15) * D_ + rg * 8;
    const short8 a0 = *(const short8*)qrow;
    const short8 a1 = *(const short8*)(qrow + 32);
    la[0] = la[1] = la[2] = la[3] = 0.0f;
#pragma unroll
    for (int ck = 0; ck < 4; ++ck) {
      const int s = h * 4 + ck;
      if (s < 31) {
        const int s1 = s + 1;
        const unsigned short* g = gwave + (size_t)(s1 >> 2) * 65536 + (size_t)(s1 & 3) * 16384;
        unsigned short* lp = &Ks[s1 & 1][wave][0];
#pragma unroll
        for (int c = 0; c < 4; ++c) GL2LDS16(g + c * 512, lp + c * 512);
        WAIT_VMCNT4();
      } else {
        WAIT_VMCNT0();  // nothing issued after the last batch: full drain
      }
      const unsigned short* kw = &Ks[s & 1][wave][ln15 * 64];
#pragma unroll
      for (int jt = 0; jt < 2; ++jt) {
        const unsigned short* kp = kw + jt * 1024;
        const short8 b0 = *(const short8*)(kp + pfrag);
        const short8 b1 = *(const short8*)(kp + (pfrag ^ 32));
        f32x4 cc = {0.0f, 0.0f, 0.0f, 0.0f};
        cc = __builtin_amdgcn_mfma_f32_16x16x32_bf16(a0, b0, cc, 0, 0, 0);
        cc = __builtin_amdgcn_mfma_f32_16x16x32_bf16(a1, b1, cc, 0, 0, 0);
#pragma unroll
        for (int r = 0; r < 4; ++r) {
          const float sv = fminf(cc[r] * QSCALE, SCLAMP);
          const float e2 = __builtin_amdgcn_exp2f(sv);
          const float ev = (mbits & (1u << (ck * 8 + jt * 4 + r))) ? 0.0f : e2;
          ef[ck][jt][r] = ev;
          la[r] += ev;
        }
      }
    }
    // wave-local l over the 16 key-lanes, then 8-wave exchange
#pragma unroll
    for (int r = 0; r < 4; ++r) la[r] = dpp_red16(la[r]);
    if (ln15 == 0) *(f32x4*)&l_lds[h & 1][wave][rg * 4] = (f32x4){la[0], la[1], la[2], la[3]};
    BARRIER_LGKM();  // ONE raw barrier per head: l exchange only, DMAs stay in flight
    // cross-wave reduce: lane reads wave-(ln15&7)'s partial, 8-lane DPP sum
    const f32x4 pw = *(const f32x4*)&l_lds[h & 1][ln15 & 7][rg * 4];
#pragma unroll
    for (int r = 0; r < 4; ++r) {
      const float li = __builtin_amdgcn_rcpf(dpp_red8(pw[r]));
#pragma unroll
      for (int ck = 0; ck < 4; ++ck)
#pragma unroll
        for (int jt = 0; jt < 2; ++jt) o[ck][jt][r] += ef[ck][jt][r] * li;
    }
  }
  // merge head-halves: HW fp32 atomic add into zeroed out (2 adds/element,
  // commutative -> deterministic). 64B contiguous per (ck,jt,r).
#pragma unroll
  for (int ck = 0; ck < 4; ++ck)
#pragma unroll
    for (int jt = 0; jt < 2; ++jt)
#pragma unroll
      for (int r = 0; r < 4; ++r)
        unsafeAtomicAdd(&out[((size_t)b * S_ + q0 + rg * 4 + r) * S_ +
                             ck * 256 + wave * 32 + jt * 16 + ln15],
                        o[ck][jt][r] * 0.0625f);
}

extern "C" void kernel_launch(void* const* d_in, const int* in_sizes, int n_in,
                              void* d_out, int out_size, void* d_ws, size_t ws_size,
                              hipStream_t stream) {
  const float* x = (const float*)d_in[0];
  const int* mask = (const int*)d_in[1];
  const float* Wq = (const float*)d_in[2];
  const float* bq = (const float*)d_in[3];
  const float* Wk = (const float*)d_in[4];
  const float* bk = (const float*)d_in[5];
  const float* gq = (const float*)d_in[6];
  const float* bq_n = (const float*)d_in[7];
  const float* gk = (const float*)d_in[8];
  const float* bk_n = (const float*)d_in[9];
  float* out = (float*)d_out;

  char* ws = (char*)d_ws;
  const size_t MB = 1024 * 1024;

  if (ws_size >= 40 * MB) {
    // fused layout (40 MB): P2 bf16 [4096][2048] @0 (16), xbf @16 (8, Kbf aliases),
    // Wt @24 (4), Qbf @28 (8), msym @36 (4)
    unsigned short* P2 = (unsigned short*)ws;
    unsigned short* xbf = (unsigned short*)(ws + 16 * MB);
    unsigned short* Kbf = (unsigned short*)(ws + 16 * MB);   // alias: xbf dead after gemm
    unsigned short* Wt = (unsigned short*)(ws + 24 * MB);
    unsigned short* Qbf = (unsigned short*)(ws + 28 * MB);
    unsigned char* msym = (unsigned char*)(ws + 36 * MB);

    prep_kernel<<<8192, 256, 0, stream>>>(mask, x, Wq, Wk, msym, xbf, Wt);
    gemm_mfma_kernel<<<512, 256, 0, stream>>>(xbf, Wt, P2, 2048);
    ln2_kernel<<<8192, 256, 0, stream>>>(P2, bq, gq, bq_n, bk, gk, bk_n, Qbf, Kbf);
    attn18_kernel<<<512, 512, 0, stream>>>(Qbf, Kbf, msym, out);
  } else {
    // split layout (32 MB): P bf16 [4096][1024] @0 (8), xbf @8 (8, Kbf aliases),
    // Wt @16 (4), Qbf @20 (8), msym @28 (4)
    unsigned short* P = (unsigned short*)ws;
    unsigned short* xbf = (unsigned short*)(ws + 8 * MB);
    unsigned short* Kbf = (unsigned short*)(ws + 8 * MB);    // alias: xbf dead after 2nd gemm
    unsigned short* Wt = (unsigned short*)(ws + 16 * MB);
    unsigned short* Qbf = (unsigned short*)(ws + 20 * MB);
    unsigned char* msym = (unsigned char*)(ws + 28 * MB);

    prep_kernel<<<8192, 256, 0, stream>>>(mask, x, Wq, Wk, msym, xbf, Wt);
    gemm_mfma_kernel<<<256, 256, 0, stream>>>(xbf, Wt, P, 1024);
    ln_relu_bf_kernel<<<4096, 256, 0, stream>>>(P, 1024, 0, bq, gq, bq_n, Qbf);
    gemm_mfma_kernel<<<256, 256, 0, stream>>>(xbf, Wt + (size_t)1024 * 1024, P, 1024);
    ln_relu_bf_kernel<<<4096, 256, 0, stream>>>(P, 1024, 0, bk, gk, bk_n, Kbf);
    attn18_kernel<<<512, 512, 0, stream>>>(Qbf, Kbf, msym, out);
  }
}

// Round 10
// 191.528 us; speedup vs baseline: 1.4640x; 1.0035x over previous
//
#include <hip/hip_runtime.h>
#include <hip/hip_bf16.h>

#define B_ 4
#define S_ 1024
#define E_ 1024
#define H_ 16
#define D_ 64

typedef __attribute__((ext_vector_type(8))) short short8;
typedef __attribute__((ext_vector_type(4))) float f32x4;

static __device__ __forceinline__ unsigned short f2bf(float x) {
  unsigned int u = __float_as_uint(x);
  unsigned int r = u + 0x7fffu + ((u >> 16) & 1u);  // round-to-nearest-even
  return (unsigned short)(r >> 16);
}
static __device__ __forceinline__ float bf2f(unsigned short b) {
  return __uint_as_float((unsigned int)b << 16);
}

#define GL2LDS16(g, l)                                                            \
  __builtin_amdgcn_global_load_lds(                                               \
      (const __attribute__((address_space(1))) unsigned int*)(g),                 \
      (__attribute__((address_space(3))) unsigned int*)(l), 16, 0, 0)

// gfx9 s_waitcnt imm: vmcnt[3:0]|[15:14], expcnt[6:4], lgkmcnt[11:8].
#define WAIT_VMCNT4() __builtin_amdgcn_s_waitcnt(0x0F74)
#define WAIT_VMCNT0() __builtin_amdgcn_s_waitcnt(0x0F70)

// Raw barrier WITHOUT the vmcnt(0) drain __syncthreads would emit.
// Legal: K staging is wave-private; only the l_lds exchange needs visibility.
#define BARRIER_LGKM()                                      \
  do {                                                      \
    asm volatile("s_waitcnt lgkmcnt(0)" ::: "memory");      \
    __builtin_amdgcn_s_barrier();                           \
  } while (0)

// combined scale: (1/sqrt(D)) * log2(e) applied in-register to the MFMA score,
// so exp() is a single v_exp_f32 (2^x). Q/K stored UNSCALED.
#define QSCALE 0.18033688011112042f
#define SCLAMP 115.41560327111707f  // 80 * log2(e)

// 16-lane sum via DPP: xor1, xor2, half-mirror, row-mirror.
static __device__ __forceinline__ float dpp_red16(float v) {
  v += __int_as_float(__builtin_amdgcn_update_dpp(0, __float_as_int(v), 0xB1, 0xF, 0xF, true));   // quad_perm [1,0,3,2]
  v += __int_as_float(__builtin_amdgcn_update_dpp(0, __float_as_int(v), 0x4E, 0xF, 0xF, true));   // quad_perm [2,3,0,1]
  v += __int_as_float(__builtin_amdgcn_update_dpp(0, __float_as_int(v), 0x141, 0xF, 0xF, true));  // row_half_mirror
  v += __int_as_float(__builtin_amdgcn_update_dpp(0, __float_as_int(v), 0x140, 0xF, 0xF, true));  // row_mirror
  return v;
}

// ---------- fused preprocessing: mask|mask^T, x->bf16, W->Wt bf16 ----------
// blocks 0..4095: mask_sym; 4096..6143: cvt_x; 6144..8191: wt transpose
__global__ __launch_bounds__(256) void prep_kernel(const int* __restrict__ mask,
                                                   const float* __restrict__ x,
                                                   const float* __restrict__ Wq,
                                                   const float* __restrict__ Wk,
                                                   unsigned char* __restrict__ msym,
                                                   unsigned short* __restrict__ xbf,
                                                   unsigned short* __restrict__ Wt) {
  __shared__ __align__(16) char u_lds[32 * 33 * 4];
  const int blk = blockIdx.x;
  const int tid = threadIdx.x;
  if (blk < 4096) {
    int (*T)[33] = (int(*)[33])u_lds;
    const int b = blk >> 10;
    const int rest = blk & 1023;
    const int i0 = (rest >> 5) << 5;
    const int j0 = (rest & 31) << 5;
    const int ii = tid >> 3;
    const int jj4 = (tid & 7) << 2;
    const size_t bO = (size_t)b * S_ * S_;
    const int4 m2 = *(const int4*)&mask[bO + (size_t)(j0 + ii) * S_ + i0 + jj4];
    T[ii][jj4 + 0] = m2.x; T[ii][jj4 + 1] = m2.y; T[ii][jj4 + 2] = m2.z; T[ii][jj4 + 3] = m2.w;
    __syncthreads();
    const int4 m1 = *(const int4*)&mask[bO + (size_t)(i0 + ii) * S_ + j0 + jj4];
    uchar4 o;
    o.x = ((m1.x != 0) || (T[jj4 + 0][ii] != 0)) ? 1 : 0;
    o.y = ((m1.y != 0) || (T[jj4 + 1][ii] != 0)) ? 1 : 0;
    o.z = ((m1.z != 0) || (T[jj4 + 2][ii] != 0)) ? 1 : 0;
    o.w = ((m1.w != 0) || (T[jj4 + 3][ii] != 0)) ? 1 : 0;
    *(uchar4*)&msym[bO + (size_t)(i0 + ii) * S_ + j0 + jj4] = o;
  } else if (blk < 6144) {
    const size_t i = ((size_t)(blk - 4096) * 256 + tid) * 8;
    const float4 a = *(const float4*)(x + i);
    const float4 b = *(const float4*)(x + i + 4);
    const ushort4 p0 = {f2bf(a.x), f2bf(a.y), f2bf(a.z), f2bf(a.w)};
    const ushort4 p1 = {f2bf(b.x), f2bf(b.y), f2bf(b.z), f2bf(b.w)};
    *(ushort4*)(xbf + i) = p0;
    *(ushort4*)(xbf + i + 4) = p1;
  } else {
    unsigned short (*T2)[36] = (unsigned short(*)[36])u_lds;
    const int wblk = blk - 6144;           // 2 * 32 * 32
    const int mat = wblk >> 10;
    const int kt = (wblk >> 5) & 31, ntb = wblk & 31;
    const float* W = mat ? Wk : Wq;
    const int r = tid >> 3, c4 = (tid & 7) << 2;
    const float4 v = *(const float4*)&W[(size_t)(kt * 32 + r) * 1024 + ntb * 32 + c4];
    T2[r][c4 + 0] = f2bf(v.x); T2[r][c4 + 1] = f2bf(v.y);
    T2[r][c4 + 2] = f2bf(v.z); T2[r][c4 + 3] = f2bf(v.w);
    __syncthreads();
    const ushort4 o = {T2[c4 + 0][r], T2[c4 + 1][r], T2[c4 + 2][r], T2[c4 + 3][r]};
    *(ushort4*)&Wt[(size_t)(mat * 1024 + ntb * 32 + r) * 1024 + kt * 32 + c4] = o;
  }
}

// ------- bf16 MFMA GEMM, BK=64: P[4096][nstride] = xbf[4096][1024] @ Wt^T --------
// blockIdx XCD-swizzled (bijective: gridDim.x % 8 == 0) for B-panel L2 locality.
__global__ __launch_bounds__(256) void gemm_mfma_kernel(const unsigned short* __restrict__ Abf,
                                                        const unsigned short* __restrict__ Wt,
                                                        unsigned short* __restrict__ P,
                                                        int nstride) {
  __shared__ __align__(16) unsigned short As[128 * 64];  // 16 KB, [m][k]
  __shared__ __align__(16) unsigned short Bs[128 * 64];  // 16 KB, [n][k]
  const int tid = threadIdx.x;
  const int cpx = gridDim.x >> 3;                        // chunks per XCD
  const int bid = (blockIdx.x & 7) * cpx + (blockIdx.x >> 3);
  const int m0 = (bid & 31) << 7;
  const int n0 = (bid >> 5) << 7;
  const int wave = tid >> 6, lane = tid & 63;
  const int ln15 = lane & 15, rg = lane >> 4;
  const int wm = (wave & 1) << 6;
  const int wn = (wave >> 1) << 6;
  const int sr = tid >> 3;
  const int sc = (tid & 7) << 3;
  const unsigned short* gA = Abf + (size_t)(m0 + sr) * 1024 + sc;
  const unsigned short* gB = Wt + (size_t)(n0 + sr) * 1024 + sc;
  unsigned short* lA = As + tid * 8;
  unsigned short* lB = Bs + tid * 8;
  f32x4 acc[4][4];
#pragma unroll
  for (int i = 0; i < 4; ++i)
#pragma unroll
    for (int j = 0; j < 4; ++j) acc[i][j] = (f32x4){0.0f, 0.0f, 0.0f, 0.0f};

  const unsigned short* pa = As + (wm + ln15) * 64 + rg * 8;
  const unsigned short* pb = Bs + (wn + ln15) * 64 + rg * 8;
  for (int k0 = 0; k0 < E_; k0 += 64) {
#pragma unroll
    for (int j = 0; j < 4; ++j) {
      GL2LDS16(gA + k0 + (size_t)(j * 32) * 1024, lA + j * 2048);
      GL2LDS16(gB + k0 + (size_t)(j * 32) * 1024, lB + j * 2048);
    }
    __syncthreads();
#pragma unroll
    for (int kk = 0; kk < 2; ++kk) {
      short8 af[4], bfr[4];
#pragma unroll
      for (int i = 0; i < 4; ++i) af[i] = *(const short8*)(pa + i * 16 * 64 + kk * 32);
#pragma unroll
      for (int j = 0; j < 4; ++j) bfr[j] = *(const short8*)(pb + j * 16 * 64 + kk * 32);
#pragma unroll
      for (int i = 0; i < 4; ++i)
#pragma unroll
        for (int j = 0; j < 4; ++j)
          acc[i][j] = __builtin_amdgcn_mfma_f32_16x16x32_bf16(af[i], bfr[j], acc[i][j], 0, 0, 0);
    }
    __syncthreads();
  }
#pragma unroll
  for (int i = 0; i < 4; ++i)
#pragma unroll
    for (int j = 0; j < 4; ++j)
#pragma unroll
      for (int r = 0; r < 4; ++r) {
        const int row = m0 + wm + i * 16 + rg * 4 + r;
        const int col = n0 + wn + j * 16 + ln15;
        P[(size_t)row * nstride + col] = f2bf(acc[i][j][r]);
      }
}

// ---- bias+LN+ReLU, WAVE-PER-ROW: no LDS, no barrier ----
// Each wave owns one full 1024-elem row: 16 elems/lane, reduction = one
// 6-hop shfl_xor butterfly (wave-local). Replaces the old 1-row-per-block
// kernel (8192 blocks, cross-wave LDS reduce + __syncthreads each).
// Emits bf16 head-major [b*16+h][s][d]; h = lane>>2, d = (lane&3)*16.
__device__ __forceinline__ void ln_wave(const unsigned short* p, const float* bias,
                                        const float* gamma, const float* beta,
                                        unsigned short* obf, int b, int s, int lane) {
  const int d0 = lane << 4;  // 16 elems per lane
  const short8 q0 = *(const short8*)(p + d0);
  const short8 q1 = *(const short8*)(p + d0 + 8);
  float v[16];
#pragma unroll
  for (int i = 0; i < 8; ++i) {
    v[i] = bf2f((unsigned short)q0[i]);
    v[8 + i] = bf2f((unsigned short)q1[i]);
  }
  const float4 bb0 = *(const float4*)(bias + d0);
  const float4 bb1 = *(const float4*)(bias + d0 + 4);
  const float4 bb2 = *(const float4*)(bias + d0 + 8);
  const float4 bb3 = *(const float4*)(bias + d0 + 12);
  v[0] += bb0.x; v[1] += bb0.y; v[2] += bb0.z; v[3] += bb0.w;
  v[4] += bb1.x; v[5] += bb1.y; v[6] += bb1.z; v[7] += bb1.w;
  v[8] += bb2.x; v[9] += bb2.y; v[10] += bb2.z; v[11] += bb2.w;
  v[12] += bb3.x; v[13] += bb3.y; v[14] += bb3.z; v[15] += bb3.w;
  float sum = 0.0f, s2 = 0.0f;
#pragma unroll
  for (int i = 0; i < 16; ++i) {
    sum += v[i];
    s2 += v[i] * v[i];
  }
#pragma unroll
  for (int off = 32; off >= 1; off >>= 1) {
    sum += __shfl_xor(sum, off);
    s2 += __shfl_xor(s2, off);
  }
  const float mu = sum * (1.0f / E_);
  const float var = s2 * (1.0f / E_) - mu * mu;
  const float r = rsqrtf(var + 1e-5f);
  const float4 g0 = *(const float4*)(gamma + d0);
  const float4 g1 = *(const float4*)(gamma + d0 + 4);
  const float4 g2 = *(const float4*)(gamma + d0 + 8);
  const float4 g3 = *(const float4*)(gamma + d0 + 12);
  const float4 t0 = *(const float4*)(beta + d0);
  const float4 t1 = *(const float4*)(beta + d0 + 4);
  const float4 t2 = *(const float4*)(beta + d0 + 8);
  const float4 t3 = *(const float4*)(beta + d0 + 12);
  const float gg[16] = {g0.x, g0.y, g0.z, g0.w, g1.x, g1.y, g1.z, g1.w,
                        g2.x, g2.y, g2.z, g2.w, g3.x, g3.y, g3.z, g3.w};
  const float tt[16] = {t0.x, t0.y, t0.z, t0.w, t1.x, t1.y, t1.z, t1.w,
                        t2.x, t2.y, t2.z, t2.w, t3.x, t3.y, t3.z, t3.w};
  short8 o0, o1;
#pragma unroll
  for (int i = 0; i < 8; ++i) {
    o0[i] = (short)f2bf(fmaxf((v[i] - mu) * r * gg[i] + tt[i], 0.0f));
    o1[i] = (short)f2bf(fmaxf((v[8 + i] - mu) * r * gg[8 + i] + tt[8 + i], 0.0f));
  }
  const int h = lane >> 2;
  const int d = (lane & 3) << 4;
  unsigned short* op = &obf[((size_t)(b * H_ + h) * S_ + s) * D_ + d];
  *(short8*)op = o0;
  *(short8*)(op + 8) = o1;
}

// split-path LN: grid 1024 x 256 (4 waves = 4 rows/block), 4096 rows
__global__ __launch_bounds__(256) void ln_relu_bf_kernel(const unsigned short* __restrict__ P,
                                                         int rowstride, int coloff,
                                                         const float* __restrict__ bias,
                                                         const float* __restrict__ gamma,
                                                         const float* __restrict__ beta,
                                                         unsigned short* __restrict__ obf) {
  const int g = blockIdx.x * 4 + (threadIdx.x >> 6);
  ln_wave(P + (size_t)g * rowstride + coloff, bias, gamma, beta, obf,
          g >> 10, g & 1023, threadIdx.x & 63);
}

// fused both-LN launch (40MB path): grid 2048 x 256, rows 0..4095 -> Q, 4096..8191 -> K
__global__ __launch_bounds__(256) void ln2_kernel(const unsigned short* __restrict__ P2,
                                                  const float* __restrict__ bq,
                                                  const float* __restrict__ gq,
                                                  const float* __restrict__ bqn,
                                                  const float* __restrict__ bk,
                                                  const float* __restrict__ gk,
                                                  const float* __restrict__ bkn,
                                                  unsigned short* __restrict__ Qbf,
                                                  unsigned short* __restrict__ Kbf) {
  const int g = blockIdx.x * 4 + (threadIdx.x >> 6);
  const int sel = g >> 12;
  const int row = g & 4095;
  ln_wave(P2 + (size_t)row * 2048 + sel * 1024,
          sel ? bk : bq, sel ? gk : gq, sel ? bkn : bqn,
          sel ? Kbf : Qbf, row >> 10, row & 1023, threadIdx.x & 63);
}

// ======= attention v15 (best: 52.6 us): wave-private DMA staging, raw barrier =======
// Byte-identical to round-6 attn15. Six restructurings (direct-load, reg-prefetch,
// two-pass, 16-key step, 8-wave split) all lost to this design; it stays.
__global__ __launch_bounds__(1024, 4) void attn15_kernel(const unsigned short* __restrict__ Qbf,
                                                         const unsigned short* __restrict__ Kbf,
                                                         const unsigned char* __restrict__ msym,
                                                         float* __restrict__ out) {
  __shared__ __align__(16) unsigned short Ks[2][16][2048];  // [par][wave][32 keys x 64] 128 KB
  __shared__ __align__(16) float l_lds[2][16][20];          // [par][wave][q, pad 20] 2.5 KB
  const int tid = threadIdx.x;
  const int wave = tid >> 6, lane = tid & 63;
  const int ln15 = lane & 15, rg = lane >> 4;
  const int b = blockIdx.x & 3;                 // XCD swizzle: K[b] L2-resident
  const int q0 = (blockIdx.x >> 2) << 4;
  const unsigned short* Kb = Kbf + (size_t)b * H_ * S_ * D_;
  const unsigned short* Qb = Qbf + (size_t)b * H_ * S_ * D_;

  // mask bits: bit(hf*8 + jt*4 + r) = msym[q0+rg*4+r][hf*512 + wave*32 + jt*16 + ln15]
  unsigned int mbits = 0;
#pragma unroll
  for (int hf = 0; hf < 2; ++hf)
#pragma unroll
    for (int jt = 0; jt < 2; ++jt)
#pragma unroll
      for (int r = 0; r < 4; ++r)
        mbits |= (msym[((size_t)b * S_ + q0 + rg * 4 + r) * S_ + hf * 512 + wave * 32 + jt * 16 + ln15]
                      ? 1u : 0u) << (hf * 8 + jt * 4 + r);
  float mf[2][2][4];
#pragma unroll
  for (int hf = 0; hf < 2; ++hf)
#pragma unroll
    for (int jt = 0; jt < 2; ++jt)
#pragma unroll
      for (int r = 0; r < 4; ++r)
        mf[hf][jt][r] = ((mbits >> (hf * 8 + jt * 4 + r)) & 1u) ? 0.0f : 1.0f;

  // DMA lane mapping (shorts): key_local = i*8 + (lane>>3), phys slot = lane&7,
  // global chunk = (lane&7) ^ (lane>>3)  [XOR swizzle]
  const int gl = ((lane >> 3) << 6) + (((lane & 7) ^ (lane >> 3)) << 3);
  const unsigned short* gwave = Kb + wave * 2048 + gl;   // + hf*32768 + h*65536 + i*512
#pragma unroll
  for (int c = 0; c < 4; ++c) GL2LDS16(gwave + c * 512, &Ks[0][wave][c * 512]);

  const int pfrag = (rg ^ (ln15 & 7)) * 8;  // swizzled chunk offset (shorts)
  float o[2][2][4] = {};
  float ef[2][2][4];
  float la[4];

#pragma unroll 1
  for (int h = 0; h < 16; ++h) {
    const unsigned short* qrow = Qb + ((size_t)h * S_ + q0 + ln15) * D_ + rg * 8;
    const short8 a0 = *(const short8*)qrow;
    const short8 a1 = *(const short8*)(qrow + 32);
    la[0] = la[1] = la[2] = la[3] = 0.0f;
#pragma unroll
    for (int hf = 0; hf < 2; ++hf) {
      const int s = h * 2 + hf;
      if (s < 31) {
        const int s1 = s + 1;
        const unsigned short* g = gwave + (size_t)(s1 >> 1) * 65536 + (s1 & 1) * 32768;
        unsigned short* lp = &Ks[s1 & 1][wave][0];
#pragma unroll
        for (int c = 0; c < 4; ++c) GL2LDS16(g + c * 512, lp + c * 512);
        WAIT_VMCNT4();
      } else {
        WAIT_VMCNT0();  // nothing issued after the last batch: full drain
      }
      const unsigned short* kw = &Ks[s & 1][wave][ln15 * 64];
#pragma unroll
      for (int jt = 0; jt < 2; ++jt) {
        const unsigned short* kp = kw + jt * 1024;
        const short8 b0 = *(const short8*)(kp + pfrag);
        const short8 b1 = *(const short8*)(kp + (pfrag ^ 32));
        f32x4 cc = {0.0f, 0.0f, 0.0f, 0.0f};
        cc = __builtin_amdgcn_mfma_f32_16x16x32_bf16(a0, b0, cc, 0, 0, 0);
        cc = __builtin_amdgcn_mfma_f32_16x16x32_bf16(a1, b1, cc, 0, 0, 0);
#pragma unroll
        for (int r = 0; r < 4; ++r) {
          const float sv = fminf(cc[r] * QSCALE, SCLAMP);
          const float ev = __builtin_amdgcn_exp2f(sv) * mf[hf][jt][r];
          ef[hf][jt][r] = ev;
          la[r] += ev;
        }
      }
    }
#pragma unroll
    for (int r = 0; r < 4; ++r) la[r] = dpp_red16(la[r]);
    if (ln15 == 0) *(f32x4*)&l_lds[h & 1][wave][rg * 4] = (f32x4){la[0], la[1], la[2], la[3]};
    BARRIER_LGKM();  // ONE raw barrier per head: l exchange only, DMAs stay in flight
    const f32x4 pw = *(const f32x4*)&l_lds[h & 1][ln15][rg * 4];
#pragma unroll
    for (int r = 0; r < 4; ++r) {
      const float li = __builtin_amdgcn_rcpf(dpp_red16(pw[r]));  // 1/16 folded into store
#pragma unroll
      for (int hf = 0; hf < 2; ++hf)
#pragma unroll
        for (int jt = 0; jt < 2; ++jt) o[hf][jt][r] += ef[hf][jt][r] * li;
    }
  }
#pragma unroll
  for (int hf = 0; hf < 2; ++hf)
#pragma unroll
    for (int jt = 0; jt < 2; ++jt)
#pragma unroll
      for (int r = 0; r < 4; ++r)
        out[((size_t)b * S_ + q0 + rg * 4 + r) * S_ + hf * 512 + wave * 32 + jt * 16 + ln15] =
            o[hf][jt][r] * 0.0625f;
}

extern "C" void kernel_launch(void* const* d_in, const int* in_sizes, int n_in,
                              void* d_out, int out_size, void* d_ws, size_t ws_size,
                              hipStream_t stream) {
  const float* x = (const float*)d_in[0];
  const int* mask = (const int*)d_in[1];
  const float* Wq = (const float*)d_in[2];
  const float* bq = (const float*)d_in[3];
  const float* Wk = (const float*)d_in[4];
  const float* bk = (const float*)d_in[5];
  const float* gq = (const float*)d_in[6];
  const float* bq_n = (const float*)d_in[7];
  const float* gk = (const float*)d_in[8];
  const float* bk_n = (const float*)d_in[9];
  float* out = (float*)d_out;

  char* ws = (char*)d_ws;
  const size_t MB = 1024 * 1024;

  if (ws_size >= 40 * MB) {
    // fused layout (40 MB): P2 bf16 [4096][2048] @0 (16), xbf @16 (8, Kbf aliases),
    // Wt @24 (4), Qbf @28 (8), msym @36 (4)
    unsigned short* P2 = (unsigned short*)ws;
    unsigned short* xbf = (unsigned short*)(ws + 16 * MB);
    unsigned short* Kbf = (unsigned short*)(ws + 16 * MB);   // alias: xbf dead after gemm
    unsigned short* Wt = (unsigned short*)(ws + 24 * MB);
    unsigned short* Qbf = (unsigned short*)(ws + 28 * MB);
    unsigned char* msym = (unsigned char*)(ws + 36 * MB);

    prep_kernel<<<8192, 256, 0, stream>>>(mask, x, Wq, Wk, msym, xbf, Wt);
    gemm_mfma_kernel<<<512, 256, 0, stream>>>(xbf, Wt, P2, 2048);
    ln2_kernel<<<2048, 256, 0, stream>>>(P2, bq, gq, bq_n, bk, gk, bk_n, Qbf, Kbf);
    attn15_kernel<<<256, 1024, 0, stream>>>(Qbf, Kbf, msym, out);
  } else {
    // split layout (32 MB): P bf16 [4096][1024] @0 (8), xbf @8 (8, Kbf aliases),
    // Wt @16 (4), Qbf @20 (8), msym @28 (4)
    unsigned short* P = (unsigned short*)ws;
    unsigned short* xbf = (unsigned short*)(ws + 8 * MB);
    unsigned short* Kbf = (unsigned short*)(ws + 8 * MB);    // alias: xbf dead after 2nd gemm
    unsigned short* Wt = (unsigned short*)(ws + 16 * MB);
    unsigned short* Qbf = (unsigned short*)(ws + 20 * MB);
    unsigned char* msym = (unsigned char*)(ws + 28 * MB);

    prep_kernel<<<8192, 256, 0, stream>>>(mask, x, Wq, Wk, msym, xbf, Wt);
    gemm_mfma_kernel<<<256, 256, 0, stream>>>(xbf, Wt, P, 1024);
    ln_relu_bf_kernel<<<1024, 256, 0, stream>>>(P, 1024, 0, bq, gq, bq_n, Qbf);
    gemm_mfma_kernel<<<256, 256, 0, stream>>>(xbf, Wt + (size_t)1024 * 1024, P, 1024);
    ln_relu_bf_kernel<<<1024, 256, 0, stream>>>(P, 1024, 0, bk, gk, bk_n, Kbf);
    attn15_kernel<<<256, 1024, 0, stream>>>(Qbf, Kbf, msym, out);
  }
}

// Round 11
// 181.567 us; speedup vs baseline: 1.5443x; 1.0549x over previous
//
#include <hip/hip_runtime.h>
#include <hip/hip_bf16.h>

#define B_ 4
#define S_ 1024
#define E_ 1024
#define H_ 16
#define D_ 64

typedef __attribute__((ext_vector_type(8))) short short8;
typedef __attribute__((ext_vector_type(4))) float f32x4;

static __device__ __forceinline__ unsigned short f2bf(float x) {
  unsigned int u = __float_as_uint(x);
  unsigned int r = u + 0x7fffu + ((u >> 16) & 1u);  // round-to-nearest-even
  return (unsigned short)(r >> 16);
}
static __device__ __forceinline__ float bf2f(unsigned short b) {
  return __uint_as_float((unsigned int)b << 16);
}

#define GL2LDS16(g, l)                                                            \
  __builtin_amdgcn_global_load_lds(                                               \
      (const __attribute__((address_space(1))) unsigned int*)(g),                 \
      (__attribute__((address_space(3))) unsigned int*)(l), 16, 0, 0)

// gfx9 s_waitcnt imm: vmcnt[3:0]|[15:14], expcnt[6:4], lgkmcnt[11:8].
#define WAIT_VMCNT4() __builtin_amdgcn_s_waitcnt(0x0F74)
#define WAIT_VMCNT0() __builtin_amdgcn_s_waitcnt(0x0F70)

// Raw barrier WITHOUT the vmcnt(0) drain __syncthreads would emit.
// Legal: K staging is wave-private; only the l_lds exchange needs visibility.
#define BARRIER_LGKM()                                      \
  do {                                                      \
    asm volatile("s_waitcnt lgkmcnt(0)" ::: "memory");      \
    __builtin_amdgcn_s_barrier();                           \
  } while (0)

// combined scale: (1/sqrt(D)) * log2(e) applied in-register to the MFMA score,
// so exp() is a single v_exp_f32 (2^x). Q/K stored UNSCALED.
#define QSCALE 0.18033688011112042f
#define SCLAMP 115.41560327111707f  // 80 * log2(e)

// 16-lane sum via DPP: xor1, xor2, half-mirror, row-mirror.
static __device__ __forceinline__ float dpp_red16(float v) {
  v += __int_as_float(__builtin_amdgcn_update_dpp(0, __float_as_int(v), 0xB1, 0xF, 0xF, true));   // quad_perm [1,0,3,2]
  v += __int_as_float(__builtin_amdgcn_update_dpp(0, __float_as_int(v), 0x4E, 0xF, 0xF, true));   // quad_perm [2,3,0,1]
  v += __int_as_float(__builtin_amdgcn_update_dpp(0, __float_as_int(v), 0x141, 0xF, 0xF, true));  // row_half_mirror
  v += __int_as_float(__builtin_amdgcn_update_dpp(0, __float_as_int(v), 0x140, 0xF, 0xF, true));  // row_mirror
  return v;
}

// ---------- fused preprocessing: mask|mask^T, x->bf16, W->Wt bf16 ----------
// blocks 0..4095: mask_sym PAIRED (ti<=tj blocks produce BOTH msym(ti,tj) and
// msym(tj,ti) from one read of each tile -> mask read traffic halves, 32->17MB);
// 4096..6143: cvt_x; 6144..8191: wt transpose
__global__ __launch_bounds__(256) void prep_kernel(const int* __restrict__ mask,
                                                   const float* __restrict__ x,
                                                   const float* __restrict__ Wq,
                                                   const float* __restrict__ Wk,
                                                   unsigned char* __restrict__ msym,
                                                   unsigned short* __restrict__ xbf,
                                                   unsigned short* __restrict__ Wt) {
  __shared__ __align__(16) char u_lds[2 * 32 * 33 * 4];
  const int blk = blockIdx.x;
  const int tid = threadIdx.x;
  if (blk < 4096) {
    const int b = blk >> 10;
    const int rest = blk & 1023;
    const int ti = rest >> 5;
    const int tj = rest & 31;
    if (ti > tj) return;  // uniform per-block: no divergent barrier
    int (*TA)[33] = (int(*)[33])u_lds;
    int (*TB)[33] = (int(*)[33])(u_lds + 32 * 33 * 4);
    const int i0 = ti << 5;
    const int j0 = tj << 5;
    const int ii = tid >> 3;
    const int jj4 = (tid & 7) << 2;
    const size_t bO = (size_t)b * S_ * S_;
    const int4 a4 = *(const int4*)&mask[bO + (size_t)(i0 + ii) * S_ + j0 + jj4];
    const int4 b4 = *(const int4*)&mask[bO + (size_t)(j0 + ii) * S_ + i0 + jj4];
    TA[ii][jj4 + 0] = a4.x; TA[ii][jj4 + 1] = a4.y; TA[ii][jj4 + 2] = a4.z; TA[ii][jj4 + 3] = a4.w;
    TB[ii][jj4 + 0] = b4.x; TB[ii][jj4 + 1] = b4.y; TB[ii][jj4 + 2] = b4.z; TB[ii][jj4 + 3] = b4.w;
    __syncthreads();
    uchar4 o1, o2;
    o1.x = ((a4.x != 0) || (TB[jj4 + 0][ii] != 0)) ? 1 : 0;
    o1.y = ((a4.y != 0) || (TB[jj4 + 1][ii] != 0)) ? 1 : 0;
    o1.z = ((a4.z != 0) || (TB[jj4 + 2][ii] != 0)) ? 1 : 0;
    o1.w = ((a4.w != 0) || (TB[jj4 + 3][ii] != 0)) ? 1 : 0;
    o2.x = ((b4.x != 0) || (TA[jj4 + 0][ii] != 0)) ? 1 : 0;
    o2.y = ((b4.y != 0) || (TA[jj4 + 1][ii] != 0)) ? 1 : 0;
    o2.z = ((b4.z != 0) || (TA[jj4 + 2][ii] != 0)) ? 1 : 0;
    o2.w = ((b4.w != 0) || (TA[jj4 + 3][ii] != 0)) ? 1 : 0;
    *(uchar4*)&msym[bO + (size_t)(i0 + ii) * S_ + j0 + jj4] = o1;  // (ti,tj) tile
    *(uchar4*)&msym[bO + (size_t)(j0 + ii) * S_ + i0 + jj4] = o2;  // (tj,ti) tile
  } else if (blk < 6144) {
    const size_t i = ((size_t)(blk - 4096) * 256 + tid) * 8;
    const float4 a = *(const float4*)(x + i);
    const float4 b = *(const float4*)(x + i + 4);
    const ushort4 p0 = {f2bf(a.x), f2bf(a.y), f2bf(a.z), f2bf(a.w)};
    const ushort4 p1 = {f2bf(b.x), f2bf(b.y), f2bf(b.z), f2bf(b.w)};
    *(ushort4*)(xbf + i) = p0;
    *(ushort4*)(xbf + i + 4) = p1;
  } else {
    unsigned short (*T2)[36] = (unsigned short(*)[36])u_lds;
    const int wblk = blk - 6144;           // 2 * 32 * 32
    const int mat = wblk >> 10;
    const int kt = (wblk >> 5) & 31, ntb = wblk & 31;
    const float* W = mat ? Wk : Wq;
    const int r = tid >> 3, c4 = (tid & 7) << 2;
    const float4 v = *(const float4*)&W[(size_t)(kt * 32 + r) * 1024 + ntb * 32 + c4];
    T2[r][c4 + 0] = f2bf(v.x); T2[r][c4 + 1] = f2bf(v.y);
    T2[r][c4 + 2] = f2bf(v.z); T2[r][c4 + 3] = f2bf(v.w);
    __syncthreads();
    const ushort4 o = {T2[c4 + 0][r], T2[c4 + 1][r], T2[c4 + 2][r], T2[c4 + 3][r]};
    *(ushort4*)&Wt[(size_t)(mat * 1024 + ntb * 32 + r) * 1024 + kt * 32 + c4] = o;
  }
}

// ------- bf16 MFMA GEMM, BK=64: P[4096][nstride] = xbf[4096][1024] @ Wt^T --------
__global__ __launch_bounds__(256) void gemm_mfma_kernel(const unsigned short* __restrict__ Abf,
                                                        const unsigned short* __restrict__ Wt,
                                                        unsigned short* __restrict__ P,
                                                        int nstride) {
  __shared__ __align__(16) unsigned short As[128 * 64];  // 16 KB, [m][k]
  __shared__ __align__(16) unsigned short Bs[128 * 64];  // 16 KB, [n][k]
  const int tid = threadIdx.x;
  const int m0 = (blockIdx.x & 31) << 7;
  const int n0 = (blockIdx.x >> 5) << 7;
  const int wave = tid >> 6, lane = tid & 63;
  const int ln15 = lane & 15, rg = lane >> 4;
  const int wm = (wave & 1) << 6;
  const int wn = (wave >> 1) << 6;
  const int sr = tid >> 3;
  const int sc = (tid & 7) << 3;
  const unsigned short* gA = Abf + (size_t)(m0 + sr) * 1024 + sc;
  const unsigned short* gB = Wt + (size_t)(n0 + sr) * 1024 + sc;
  unsigned short* lA = As + tid * 8;
  unsigned short* lB = Bs + tid * 8;
  f32x4 acc[4][4];
#pragma unroll
  for (int i = 0; i < 4; ++i)
#pragma unroll
    for (int j = 0; j < 4; ++j) acc[i][j] = (f32x4){0.0f, 0.0f, 0.0f, 0.0f};

  const unsigned short* pa = As + (wm + ln15) * 64 + rg * 8;
  const unsigned short* pb = Bs + (wn + ln15) * 64 + rg * 8;
  for (int k0 = 0; k0 < E_; k0 += 64) {
#pragma unroll
    for (int j = 0; j < 4; ++j) {
      GL2LDS16(gA + k0 + (size_t)(j * 32) * 1024, lA + j * 2048);
      GL2LDS16(gB + k0 + (size_t)(j * 32) * 1024, lB + j * 2048);
    }
    __syncthreads();
#pragma unroll
    for (int kk = 0; kk < 2; ++kk) {
      short8 af[4], bfr[4];
#pragma unroll
      for (int i = 0; i < 4; ++i) af[i] = *(const short8*)(pa + i * 16 * 64 + kk * 32);
#pragma unroll
      for (int j = 0; j < 4; ++j) bfr[j] = *(const short8*)(pb + j * 16 * 64 + kk * 32);
#pragma unroll
      for (int i = 0; i < 4; ++i)
#pragma unroll
        for (int j = 0; j < 4; ++j)
          acc[i][j] = __builtin_amdgcn_mfma_f32_16x16x32_bf16(af[i], bfr[j], acc[i][j], 0, 0, 0);
    }
    __syncthreads();
  }
#pragma unroll
  for (int i = 0; i < 4; ++i)
#pragma unroll
    for (int j = 0; j < 4; ++j)
#pragma unroll
      for (int r = 0; r < 4; ++r) {
        const int row = m0 + wm + i * 16 + rg * 4 + r;
        const int col = n0 + wn + j * 16 + ln15;
        P[(size_t)row * nstride + col] = f2bf(acc[i][j][r]);
      }
}

// ---- bias+LN+ReLU from bf16 P; emit bf16 head-major [b*16+h][s][d] ----
__device__ __forceinline__ void ln_body(const unsigned short* p, const float* bias,
                                        const float* gamma, const float* beta,
                                        unsigned short* obf, int b, int s, int tid) {
  const ushort4 pv = *(const ushort4*)(p + tid * 4);
  float4 v = {bf2f(pv.x), bf2f(pv.y), bf2f(pv.z), bf2f(pv.w)};
  const float4 bb = ((const float4*)bias)[tid];
  v.x += bb.x; v.y += bb.y; v.z += bb.z; v.w += bb.w;
  float sum = v.x + v.y + v.z + v.w;
  float s2 = v.x * v.x + v.y * v.y + v.z * v.z + v.w * v.w;
#pragma unroll
  for (int off = 32; off >= 1; off >>= 1) {
    sum += __shfl_xor(sum, off);
    s2 += __shfl_xor(s2, off);
  }
  __shared__ float red[2][4];
  const int wave = tid >> 6, lane = tid & 63;
  if (lane == 0) { red[0][wave] = sum; red[1][wave] = s2; }
  __syncthreads();
  sum = red[0][0] + red[0][1] + red[0][2] + red[0][3];
  s2 = red[1][0] + red[1][1] + red[1][2] + red[1][3];
  const float mu = sum * (1.0f / E_);
  const float var = s2 * (1.0f / E_) - mu * mu;
  const float r = rsqrtf(var + 1e-5f);
  const float4 g = ((const float4*)gamma)[tid];
  const float4 bt = ((const float4*)beta)[tid];
  const float o0 = fmaxf((v.x - mu) * r * g.x + bt.x, 0.0f);
  const float o1 = fmaxf((v.y - mu) * r * g.y + bt.y, 0.0f);
  const float o2 = fmaxf((v.z - mu) * r * g.z + bt.z, 0.0f);
  const float o3 = fmaxf((v.w - mu) * r * g.w + bt.w, 0.0f);
  const int h = tid >> 4;
  const int d = (tid & 15) << 2;
  const ushort4 ob = {f2bf(o0), f2bf(o1), f2bf(o2), f2bf(o3)};
  *(ushort4*)&obf[((size_t)(b * H_ + h) * S_ + s) * D_ + d] = ob;
}

__global__ __launch_bounds__(256) void ln_relu_bf_kernel(const unsigned short* __restrict__ P,
                                                         int rowstride, int coloff,
                                                         const float* __restrict__ bias,
                                                         const float* __restrict__ gamma,
                                                         const float* __restrict__ beta,
                                                         unsigned short* __restrict__ obf) {
  const int row = blockIdx.x;
  ln_body(P + (size_t)row * rowstride + coloff, bias, gamma, beta, obf,
          row >> 10, row & 1023, threadIdx.x);
}

// fused both-LN launch (40MB path): blocks 0..4095 -> Q, 4096..8191 -> K
__global__ __launch_bounds__(256) void ln2_kernel(const unsigned short* __restrict__ P2,
                                                  const float* __restrict__ bq,
                                                  const float* __restrict__ gq,
                                                  const float* __restrict__ bqn,
                                                  const float* __restrict__ bk,
                                                  const float* __restrict__ gk,
                                                  const float* __restrict__ bkn,
                                                  unsigned short* __restrict__ Qbf,
                                                  unsigned short* __restrict__ Kbf) {
  const int blk = blockIdx.x;
  const int sel = blk >> 12;
  const int row = blk & 4095;
  ln_body(P2 + (size_t)row * 2048 + sel * 1024,
          sel ? bk : bq, sel ? gk : gq, sel ? bkn : bqn,
          sel ? Kbf : Qbf, row >> 10, row & 1023, threadIdx.x);
}

// ======= attention v15 (best: 52.6 us): wave-private DMA staging, raw barrier =======
// Byte-identical to round-6 attn15. Six restructurings (direct-load, reg-prefetch,
// two-pass, 16-key step, 8-wave split) all lost to this design; it stays.
__global__ __launch_bounds__(1024, 4) void attn15_kernel(const unsigned short* __restrict__ Qbf,
                                                         const unsigned short* __restrict__ Kbf,
                                                         const unsigned char* __restrict__ msym,
                                                         float* __restrict__ out) {
  __shared__ __align__(16) unsigned short Ks[2][16][2048];  // [par][wave][32 keys x 64] 128 KB
  __shared__ __align__(16) float l_lds[2][16][20];          // [par][wave][q, pad 20] 2.5 KB
  const int tid = threadIdx.x;
  const int wave = tid >> 6, lane = tid & 63;
  const int ln15 = lane & 15, rg = lane >> 4;
  const int b = blockIdx.x & 3;                 // XCD swizzle: K[b] L2-resident
  const int q0 = (blockIdx.x >> 2) << 4;
  const unsigned short* Kb = Kbf + (size_t)b * H_ * S_ * D_;
  const unsigned short* Qb = Qbf + (size_t)b * H_ * S_ * D_;

  // mask bits: bit(hf*8 + jt*4 + r) = msym[q0+rg*4+r][hf*512 + wave*32 + jt*16 + ln15]
  unsigned int mbits = 0;
#pragma unroll
  for (int hf = 0; hf < 2; ++hf)
#pragma unroll
    for (int jt = 0; jt < 2; ++jt)
#pragma unroll
      for (int r = 0; r < 4; ++r)
        mbits |= (msym[((size_t)b * S_ + q0 + rg * 4 + r) * S_ + hf * 512 + wave * 32 + jt * 16 + ln15]
                      ? 1u : 0u) << (hf * 8 + jt * 4 + r);
  float mf[2][2][4];
#pragma unroll
  for (int hf = 0; hf < 2; ++hf)
#pragma unroll
    for (int jt = 0; jt < 2; ++jt)
#pragma unroll
      for (int r = 0; r < 4; ++r)
        mf[hf][jt][r] = ((mbits >> (hf * 8 + jt * 4 + r)) & 1u) ? 0.0f : 1.0f;

  // DMA lane mapping (shorts): key_local = i*8 + (lane>>3), phys slot = lane&7,
  // global chunk = (lane&7) ^ (lane>>3)  [XOR swizzle]
  const int gl = ((lane >> 3) << 6) + (((lane & 7) ^ (lane >> 3)) << 3);
  const unsigned short* gwave = Kb + wave * 2048 + gl;   // + hf*32768 + h*65536 + i*512
#pragma unroll
  for (int c = 0; c < 4; ++c) GL2LDS16(gwave + c * 512, &Ks[0][wave][c * 512]);

  const int pfrag = (rg ^ (ln15 & 7)) * 8;  // swizzled chunk offset (shorts)
  float o[2][2][4] = {};
  float ef[2][2][4];
  float la[4];

#pragma unroll 1
  for (int h = 0; h < 16; ++h) {
    const unsigned short* qrow = Qb + ((size_t)h * S_ + q0 + ln15) * D_ + rg * 8;
    const short8 a0 = *(const short8*)qrow;
    const short8 a1 = *(const short8*)(qrow + 32);
    la[0] = la[1] = la[2] = la[3] = 0.0f;
#pragma unroll
    for (int hf = 0; hf < 2; ++hf) {
      const int s = h * 2 + hf;
      if (s < 31) {
        const int s1 = s + 1;
        const unsigned short* g = gwave + (size_t)(s1 >> 1) * 65536 + (s1 & 1) * 32768;
        unsigned short* lp = &Ks[s1 & 1][wave][0];
#pragma unroll
        for (int c = 0; c < 4; ++c) GL2LDS16(g + c * 512, lp + c * 512);
        WAIT_VMCNT4();
      } else {
        WAIT_VMCNT0();  // nothing issued after the last batch: full drain
      }
      const unsigned short* kw = &Ks[s & 1][wave][ln15 * 64];
#pragma unroll
      for (int jt = 0; jt < 2; ++jt) {
        const unsigned short* kp = kw + jt * 1024;
        const short8 b0 = *(const short8*)(kp + pfrag);
        const short8 b1 = *(const short8*)(kp + (pfrag ^ 32));
        f32x4 cc = {0.0f, 0.0f, 0.0f, 0.0f};
        cc = __builtin_amdgcn_mfma_f32_16x16x32_bf16(a0, b0, cc, 0, 0, 0);
        cc = __builtin_amdgcn_mfma_f32_16x16x32_bf16(a1, b1, cc, 0, 0, 0);
#pragma unroll
        for (int r = 0; r < 4; ++r) {
          const float sv = fminf(cc[r] * QSCALE, SCLAMP);
          const float ev = __builtin_amdgcn_exp2f(sv) * mf[hf][jt][r];
          ef[hf][jt][r] = ev;
          la[r] += ev;
        }
      }
    }
#pragma unroll
    for (int r = 0; r < 4; ++r) la[r] = dpp_red16(la[r]);
    if (ln15 == 0) *(f32x4*)&l_lds[h & 1][wave][rg * 4] = (f32x4){la[0], la[1], la[2], la[3]};
    BARRIER_LGKM();  // ONE raw barrier per head: l exchange only, DMAs stay in flight
    const f32x4 pw = *(const f32x4*)&l_lds[h & 1][ln15][rg * 4];
#pragma unroll
    for (int r = 0; r < 4; ++r) {
      const float li = __builtin_amdgcn_rcpf(dpp_red16(pw[r]));  // 1/16 folded into store
#pragma unroll
      for (int hf = 0; hf < 2; ++hf)
#pragma unroll
        for (int jt = 0; jt < 2; ++jt) o[hf][jt][r] += ef[hf][jt][r] * li;
    }
  }
#pragma unroll
  for (int hf = 0; hf < 2; ++hf)
#pragma unroll
    for (int jt = 0; jt < 2; ++jt)
#pragma unroll
      for (int r = 0; r < 4; ++r)
        out[((size_t)b * S_ + q0 + rg * 4 + r) * S_ + hf * 512 + wave * 32 + jt * 16 + ln15] =
            o[hf][jt][r] * 0.0625f;
}

extern "C" void kernel_launch(void* const* d_in, const int* in_sizes, int n_in,
                              void* d_out, int out_size, void* d_ws, size_t ws_size,
                              hipStream_t stream) {
  const float* x = (const float*)d_in[0];
  const int* mask = (const int*)d_in[1];
  const float* Wq = (const float*)d_in[2];
  const float* bq = (const float*)d_in[3];
  const float* Wk = (const float*)d_in[4];
  const float* bk = (const float*)d_in[5];
  const float* gq = (const float*)d_in[6];
  const float* bq_n = (const float*)d_in[7];
  const float* gk = (const float*)d_in[8];
  const float* bk_n = (const float*)d_in[9];
  float* out = (float*)d_out;

  char* ws = (char*)d_ws;
  const size_t MB = 1024 * 1024;

  if (ws_size >= 40 * MB) {
    // fused layout (40 MB): P2 bf16 [4096][2048] @0 (16), xbf @16 (8, Kbf aliases),
    // Wt @24 (4), Qbf @28 (8), msym @36 (4)
    unsigned short* P2 = (unsigned short*)ws;
    unsigned short* xbf = (unsigned short*)(ws + 16 * MB);
    unsigned short* Kbf = (unsigned short*)(ws + 16 * MB);   // alias: xbf dead after gemm
    unsigned short* Wt = (unsigned short*)(ws + 24 * MB);
    unsigned short* Qbf = (unsigned short*)(ws + 28 * MB);
    unsigned char* msym = (unsigned char*)(ws + 36 * MB);

    prep_kernel<<<8192, 256, 0, stream>>>(mask, x, Wq, Wk, msym, xbf, Wt);
    gemm_mfma_kernel<<<512, 256, 0, stream>>>(xbf, Wt, P2, 2048);
    ln2_kernel<<<8192, 256, 0, stream>>>(P2, bq, gq, bq_n, bk, gk, bk_n, Qbf, Kbf);
    attn15_kernel<<<256, 1024, 0, stream>>>(Qbf, Kbf, msym, out);
  } else {
    // split layout (32 MB): P bf16 [4096][1024] @0 (8), xbf @8 (8, Kbf aliases),
    // Wt @16 (4), Qbf @20 (8), msym @28 (4)
    unsigned short* P = (unsigned short*)ws;
    unsigned short* xbf = (unsigned short*)(ws + 8 * MB);
    unsigned short* Kbf = (unsigned short*)(ws + 8 * MB);    // alias: xbf dead after 2nd gemm
    unsigned short* Wt = (unsigned short*)(ws + 16 * MB);
    unsigned short* Qbf = (unsigned short*)(ws + 20 * MB);
    unsigned char* msym = (unsigned char*)(ws + 28 * MB);

    prep_kernel<<<8192, 256, 0, stream>>>(mask, x, Wq, Wk, msym, xbf, Wt);
    gemm_mfma_kernel<<<256, 256, 0, stream>>>(xbf, Wt, P, 1024);
    ln_relu_bf_kernel<<<4096, 256, 0, stream>>>(P, 1024, 0, bq, gq, bq_n, Qbf);
    gemm_mfma_kernel<<<256, 256, 0, stream>>>(xbf, Wt + (size_t)1024 * 1024, P, 1024);
    ln_relu_bf_kernel<<<4096, 256, 0, stream>>>(P, 1024, 0, bk, gk, bk_n, Kbf);
    attn15_kernel<<<256, 1024, 0, stream>>>(Qbf, Kbf, msym, out);
  }
}